// Round 1
// baseline (3019.376 us; speedup 1.0000x reference)
//
#include <hip/hip_runtime.h>

#define D 128
#define TWO_D 256
#define BM 32
#define BN_EPS 1e-5f

__device__ __forceinline__ float relu_f(float x) { return x > 0.f ? x : 0.f; }

// h[n][d] = atom_emb0[x0][d] + atom_emb1[x1][d]
__global__ void atom_embed_kernel(const int* __restrict__ x,
                                  const float* __restrict__ emb0,
                                  const float* __restrict__ emb1,
                                  float* __restrict__ h, int n) {
    int idx = blockIdx.x * blockDim.x + threadIdx.x;
    int total = n * (D / 4);
    if (idx >= total) return;
    int node = idx >> 5;            // D/4 == 32 float4 per row
    int d0 = (idx & 31) << 2;
    int i0 = x[node * 2 + 0];
    int i1 = x[node * 2 + 1];
    const float4 a = *reinterpret_cast<const float4*>(emb0 + (size_t)i0 * D + d0);
    const float4 b = *reinterpret_cast<const float4*>(emb1 + (size_t)i1 * D + d0);
    *reinterpret_cast<float4*>(h + (size_t)node * D + d0) =
        make_float4(a.x + b.x, a.y + b.y, a.z + b.z, a.w + b.w);
}

// aggr[n][d] = h[n][d] + ee0[4][d] + ee1[0][d]   (self-loop message, no atomics)
// block 0 also zeroes the 256 BN-stat accumulators for this layer.
__global__ void aggr_init_kernel(const float* __restrict__ h,
                                 const float* __restrict__ ee0_l,
                                 const float* __restrict__ ee1_l,
                                 float* __restrict__ aggr,
                                 float* __restrict__ stats, int n) {
    if (blockIdx.x == 0) stats[threadIdx.x] = 0.f;   // blockDim == 256
    int idx = blockIdx.x * blockDim.x + threadIdx.x;
    int total = n * (D / 4);
    if (idx >= total) return;
    int node = idx >> 5;
    int d0 = (idx & 31) << 2;
    float4 hv = *reinterpret_cast<const float4*>(h + (size_t)node * D + d0);
    float4 e0 = *reinterpret_cast<const float4*>(ee0_l + 4 * D + d0);
    float4 e1 = *reinterpret_cast<const float4*>(ee1_l + 0 * D + d0);
    *reinterpret_cast<float4*>(aggr + (size_t)node * D + d0) =
        make_float4(hv.x + e0.x + e1.x, hv.y + e0.y + e1.y,
                    hv.z + e0.z + e1.z, hv.w + e0.w + e1.w);
}

// For each real edge e: aggr[dst] += h[src] + ee0[ea0] + ee1[ea1]
// 32 lanes per edge, float4 per lane, 4 scalar native f32 atomics.
__global__ void scatter_kernel(const int* __restrict__ ei,   // [2][E]
                               const int* __restrict__ ea,   // [E][2]
                               const float* __restrict__ h,
                               const float* __restrict__ ee0_l,  // [5][D]
                               const float* __restrict__ ee1_l,  // [3][D]
                               float* __restrict__ aggr, int e_cnt) {
    int e = blockIdx.x * 8 + (threadIdx.x >> 5);
    if (e >= e_cnt) return;
    int d0 = (threadIdx.x & 31) << 2;
    int s  = ei[e];
    int t  = ei[e_cnt + e];
    int a0 = ea[e * 2 + 0];
    int a1 = ea[e * 2 + 1];
    float4 hv = *reinterpret_cast<const float4*>(h + (size_t)s * D + d0);
    float4 e0 = *reinterpret_cast<const float4*>(ee0_l + (size_t)a0 * D + d0);
    float4 e1 = *reinterpret_cast<const float4*>(ee1_l + (size_t)a1 * D + d0);
    float* dst = aggr + (size_t)t * D + d0;
    unsafeAtomicAdd(dst + 0, hv.x + e0.x + e1.x);
    unsafeAtomicAdd(dst + 1, hv.y + e0.y + e1.y);
    unsafeAtomicAdd(dst + 2, hv.z + e0.z + e1.z);
    unsafeAtomicAdd(dst + 3, hv.w + e0.w + e1.w);
}

// Fused MLP: out = (relu(A@W1+b1))@W2 + b2 for a 32-row block, plus
// per-column BN partial sums (sum, sumsq) reduced in LDS then one atomic each.
__global__ __launch_bounds__(256) void mlp_kernel(
    const float* __restrict__ aggr,
    const float* __restrict__ W1l, const float* __restrict__ b1l,
    const float* __restrict__ W2l, const float* __restrict__ b2l,
    float* __restrict__ out, float* __restrict__ stats, int n) {

    __shared__ float sA[BM * D];       // 16 KB
    __shared__ float sH[BM * TWO_D];   // 32 KB

    const int t = threadIdx.x;
    const int row0 = blockIdx.x * BM;

    // Stage A tile (zero-fill rows past n)
    #pragma unroll
    for (int i = 0; i < 4; ++i) {
        int idx = t + i * 256;          // BM*D/4 = 1024 float4
        int r  = idx >> 5;
        int c4 = (idx & 31) << 2;
        float4 v = make_float4(0.f, 0.f, 0.f, 0.f);
        if (row0 + r < n) v = *reinterpret_cast<const float4*>(aggr + (size_t)(row0 + r) * D + c4);
        *reinterpret_cast<float4*>(sA + r * D + c4) = v;
    }
    __syncthreads();

    const int tr = t >> 5;      // 0..7  -> rows r0..r0+3
    const int tc = t & 31;      // 0..31 -> cols tc*4 (+128)
    const int r0 = tr * 4;
    const int cl = tc * 4;

    // GEMM1: hid = relu(A @ W1 + b1) -> sH
    float acc[4][8];
    #pragma unroll
    for (int i = 0; i < 4; ++i)
        #pragma unroll
        for (int j = 0; j < 8; ++j) acc[i][j] = 0.f;

    #pragma unroll 4
    for (int k = 0; k < D; ++k) {
        const float4 wlo = *reinterpret_cast<const float4*>(W1l + (size_t)k * TWO_D + cl);
        const float4 whi = *reinterpret_cast<const float4*>(W1l + (size_t)k * TWO_D + cl + D);
        float a[4];
        #pragma unroll
        for (int i = 0; i < 4; ++i) a[i] = sA[(r0 + i) * D + k];
        #pragma unroll
        for (int i = 0; i < 4; ++i) {
            acc[i][0] += a[i] * wlo.x;  acc[i][1] += a[i] * wlo.y;
            acc[i][2] += a[i] * wlo.z;  acc[i][3] += a[i] * wlo.w;
            acc[i][4] += a[i] * whi.x;  acc[i][5] += a[i] * whi.y;
            acc[i][6] += a[i] * whi.z;  acc[i][7] += a[i] * whi.w;
        }
    }
    {
        const float4 blo = *reinterpret_cast<const float4*>(b1l + cl);
        const float4 bhi = *reinterpret_cast<const float4*>(b1l + cl + D);
        #pragma unroll
        for (int i = 0; i < 4; ++i) {
            float4 lo = make_float4(relu_f(acc[i][0] + blo.x), relu_f(acc[i][1] + blo.y),
                                    relu_f(acc[i][2] + blo.z), relu_f(acc[i][3] + blo.w));
            float4 hi = make_float4(relu_f(acc[i][4] + bhi.x), relu_f(acc[i][5] + bhi.y),
                                    relu_f(acc[i][6] + bhi.z), relu_f(acc[i][7] + bhi.w));
            *reinterpret_cast<float4*>(sH + (r0 + i) * TWO_D + cl)     = lo;
            *reinterpret_cast<float4*>(sH + (r0 + i) * TWO_D + cl + D) = hi;
        }
    }
    __syncthreads();

    // GEMM2: out = sH @ W2 + b2
    const int c2 = tc * 4;      // cols c2..c2+3
    float acc2[4][4];
    #pragma unroll
    for (int i = 0; i < 4; ++i)
        #pragma unroll
        for (int j = 0; j < 4; ++j) acc2[i][j] = 0.f;

    #pragma unroll 4
    for (int k = 0; k < TWO_D; ++k) {
        const float4 w = *reinterpret_cast<const float4*>(W2l + (size_t)k * D + c2);
        #pragma unroll
        for (int i = 0; i < 4; ++i) {
            float hh = sH[(r0 + i) * TWO_D + k];
            acc2[i][0] += hh * w.x;  acc2[i][1] += hh * w.y;
            acc2[i][2] += hh * w.z;  acc2[i][3] += hh * w.w;
        }
    }

    const float4 bb = *reinterpret_cast<const float4*>(b2l + c2);
    float ps[4] = {0.f, 0.f, 0.f, 0.f};
    float pq[4] = {0.f, 0.f, 0.f, 0.f};
    #pragma unroll
    for (int i = 0; i < 4; ++i) {
        int grow = row0 + r0 + i;
        if (grow < n) {
            float4 v = make_float4(acc2[i][0] + bb.x, acc2[i][1] + bb.y,
                                   acc2[i][2] + bb.z, acc2[i][3] + bb.w);
            *reinterpret_cast<float4*>(out + (size_t)grow * D + c2) = v;
            ps[0] += v.x; ps[1] += v.y; ps[2] += v.z; ps[3] += v.w;
            pq[0] += v.x * v.x; pq[1] += v.y * v.y; pq[2] += v.z * v.z; pq[3] += v.w * v.w;
        }
    }

    // Block-level BN-stat reduction (reuse sA), then one global atomic per slot.
    __syncthreads();
    float* sRed = sA;            // 256 floats: [sum(128) | sumsq(128)]
    sRed[t] = 0.f;
    __syncthreads();
    #pragma unroll
    for (int j = 0; j < 4; ++j) {
        atomicAdd(sRed + c2 + j, ps[j]);
        atomicAdd(sRed + 128 + c2 + j, pq[j]);
    }
    __syncthreads();
    unsafeAtomicAdd(stats + t, sRed[t]);
}

// scale/shift from accumulated stats
__global__ void bn_scale_kernel(const float* __restrict__ stats,
                                const float* __restrict__ gamma_l,
                                const float* __restrict__ beta_l,
                                float* __restrict__ scsh, float inv_n) {
    int c = threadIdx.x;   // 128
    float mean = stats[c] * inv_n;
    float var  = stats[128 + c] * inv_n - mean * mean;
    float sc = gamma_l[c] * rsqrtf(var + BN_EPS);
    scsh[c]       = sc;
    scsh[128 + c] = beta_l[c] - mean * sc;
}

// dst = maybe_relu(out * scale + shift)
__global__ void bn_apply_kernel(const float* __restrict__ out,
                                const float* __restrict__ scsh,
                                float* __restrict__ dst, int n, int do_relu) {
    int idx = blockIdx.x * blockDim.x + threadIdx.x;
    int total = n * (D / 4);
    if (idx >= total) return;
    int d0 = (idx & 31) << 2;
    float4 v  = *reinterpret_cast<const float4*>(out + (size_t)idx * 4);
    float4 sc = *reinterpret_cast<const float4*>(scsh + d0);
    float4 sh = *reinterpret_cast<const float4*>(scsh + 128 + d0);
    float4 r = make_float4(v.x * sc.x + sh.x, v.y * sc.y + sh.y,
                           v.z * sc.z + sh.z, v.w * sc.w + sh.w);
    if (do_relu) r = make_float4(relu_f(r.x), relu_f(r.y), relu_f(r.z), relu_f(r.w));
    *reinterpret_cast<float4*>(dst + (size_t)idx * 4) = r;
}

extern "C" void kernel_launch(void* const* d_in, const int* in_sizes, int n_in,
                              void* d_out, int out_size, void* d_ws, size_t ws_size,
                              hipStream_t stream) {
    const int*   x     = (const int*)d_in[0];
    const int*   ei    = (const int*)d_in[1];
    const int*   ea    = (const int*)d_in[2];
    const float* aemb0 = (const float*)d_in[3];
    const float* aemb1 = (const float*)d_in[4];
    const float* eemb0 = (const float*)d_in[5];
    const float* eemb1 = (const float*)d_in[6];
    const float* W1    = (const float*)d_in[7];
    const float* b1    = (const float*)d_in[8];
    const float* W2    = (const float*)d_in[9];
    const float* b2    = (const float*)d_in[10];
    const float* gamma = (const float*)d_in[11];
    const float* beta  = (const float*)d_in[12];

    const int n = in_sizes[0] / 2;          // 50000
    const int e = in_sizes[1] / 2;          // 500000
    const int L = in_sizes[8] / TWO_D;      // 3

    float* h     = (float*)d_ws;
    float* aggr  = h    + (size_t)n * D;
    float* outb  = aggr + (size_t)n * D;
    float* stats = outb + (size_t)n * D;    // 256 floats: sum | sumsq
    float* scsh  = stats + 256;             // 256 floats: scale | shift

    const int vec_blocks = (n * (D / 4) + 255) / 256;

    atom_embed_kernel<<<vec_blocks, 256, 0, stream>>>(x, aemb0, aemb1, h, n);

    for (int l = 0; l < L; ++l) {
        const float* ee0_l = eemb0 + (size_t)l * 5 * D;
        const float* ee1_l = eemb1 + (size_t)l * 3 * D;
        const float* W1l   = W1 + (size_t)l * D * TWO_D;
        const float* b1l   = b1 + (size_t)l * TWO_D;
        const float* W2l   = W2 + (size_t)l * TWO_D * D;
        const float* b2l   = b2 + (size_t)l * D;

        aggr_init_kernel<<<vec_blocks, 256, 0, stream>>>(h, ee0_l, ee1_l, aggr, stats, n);
        scatter_kernel<<<(e + 7) / 8, 256, 0, stream>>>(ei, ea, h, ee0_l, ee1_l, aggr, e);
        mlp_kernel<<<(n + BM - 1) / BM, 256, 0, stream>>>(aggr, W1l, b1l, W2l, b2l, outb, stats, n);
        bn_scale_kernel<<<1, D, 0, stream>>>(stats, gamma + (size_t)l * D, beta + (size_t)l * D,
                                             scsh, 1.0f / (float)n);
        float* dst = (l == L - 1) ? (float*)d_out : h;
        bn_apply_kernel<<<vec_blocks, 256, 0, stream>>>(outb, scsh, dst, n, (l != L - 1) ? 1 : 0);
    }
}

// Round 2
// 781.803 us; speedup vs baseline: 3.8621x; 3.8621x over previous
//
#include <hip/hip_runtime.h>

#define D 128
#define TWO_D 256
#define BM 32
#define BN_EPS 1e-5f

__device__ __forceinline__ float relu_f(float x) { return x > 0.f ? x : 0.f; }

// h[n][d] = atom_emb0[x0][d] + atom_emb1[x1][d]
__global__ void atom_embed_kernel(const int* __restrict__ x,
                                  const float* __restrict__ emb0,
                                  const float* __restrict__ emb1,
                                  float* __restrict__ h, int n) {
    int idx = blockIdx.x * blockDim.x + threadIdx.x;
    int total = n * (D / 4);
    if (idx >= total) return;
    int node = idx >> 5;            // D/4 == 32 float4 per row
    int d0 = (idx & 31) << 2;
    int i0 = x[node * 2 + 0];
    int i1 = x[node * 2 + 1];
    const float4 a = *reinterpret_cast<const float4*>(emb0 + (size_t)i0 * D + d0);
    const float4 b = *reinterpret_cast<const float4*>(emb1 + (size_t)i1 * D + d0);
    *reinterpret_cast<float4*>(h + (size_t)node * D + d0) =
        make_float4(a.x + b.x, a.y + b.y, a.z + b.z, a.w + b.w);
}

// ---- CSR build (once per launch, reused for all 3 layers) ----

// counts[dst]++ for every real edge
__global__ void hist_kernel(const int* __restrict__ ei, int* __restrict__ counts, int e_cnt) {
    int e = blockIdx.x * blockDim.x + threadIdx.x;
    if (e >= e_cnt) return;
    atomicAdd(counts + ei[e_cnt + e], 1);
}

// single-block exclusive scan over counts[n] -> row_ptr[n+1], cursor[n]=row_ptr[i]
__global__ __launch_bounds__(1024) void scan_kernel(const int* __restrict__ counts,
                                                    int* __restrict__ row_ptr,
                                                    int* __restrict__ cursor, int n) {
    __shared__ int s[1024];
    const int t = threadIdx.x;
    const int chunk = (n + 1023) / 1024;
    const int start = t * chunk;
    const int end = min(start + chunk, n);

    int sum = 0;
    for (int i = start; i < end; ++i) sum += counts[i];
    s[t] = sum;
    __syncthreads();
    // Hillis-Steele inclusive scan
    for (int off = 1; off < 1024; off <<= 1) {
        int v = (t >= off) ? s[t - off] : 0;
        __syncthreads();
        s[t] += v;
        __syncthreads();
    }
    int base = (t == 0) ? 0 : s[t - 1];
    for (int i = start; i < end; ++i) {
        int c = counts[i];
        row_ptr[i] = base;
        cursor[i] = base;
        base += c;
    }
    if (t == 0) row_ptr[n] = s[1023];
}

// epack[pos] = src | (a0*3+a1)<<17, pos = cursor[dst]++
__global__ void fill_kernel(const int* __restrict__ ei, const int* __restrict__ ea,
                            int* __restrict__ cursor, int* __restrict__ epack, int e_cnt) {
    int e = blockIdx.x * blockDim.x + threadIdx.x;
    if (e >= e_cnt) return;
    int dst = ei[e_cnt + e];
    int src = ei[e];
    int aidx = ea[e * 2 + 0] * 3 + ea[e * 2 + 1];
    int pos = atomicAdd(cursor + dst, 1);
    epack[pos] = (src & 0x1FFFF) | (aidx << 17);
}

// ---- per-layer aggregation: gather over CSR, no atomics ----
// aggr[v] = h[v] + ee0[4]+ee1[0]  +  sum_{e->v} (h[src] + ee0[a0]+ee1[a1])
// 32 lanes per node (float4 each), 8 nodes per 256-thread block.
__global__ __launch_bounds__(256) void gather_kernel(
    const float* __restrict__ h,
    const float* __restrict__ ee0_l,   // [5][D]
    const float* __restrict__ ee1_l,   // [3][D]
    const int* __restrict__ row_ptr,
    const int* __restrict__ epack,
    float* __restrict__ aggr, float* __restrict__ stats, int n) {

    __shared__ float cee[16 * D];   // rows 0..14: ee0[a/3]+ee1[a%3]; row 15: self-loop
    const int t = threadIdx.x;
    if (blockIdx.x == 0) stats[t] = 0.f;   // zero BN accumulators for this layer

    for (int idx = t; idx < 16 * D; idx += 256) {
        int r = idx >> 7, d = idx & (D - 1);
        float v;
        if (r < 15) v = ee0_l[(r / 3) * D + d] + ee1_l[(r % 3) * D + d];
        else        v = ee0_l[4 * D + d] + ee1_l[d];
        cee[idx] = v;
    }
    __syncthreads();

    int node = blockIdx.x * 8 + (t >> 5);
    if (node >= n) return;
    int d0 = (t & 31) << 2;

    float4 acc = *reinterpret_cast<const float4*>(h + (size_t)node * D + d0);
    {
        const float4 cs = *reinterpret_cast<const float4*>(cee + 15 * D + d0);
        acc.x += cs.x; acc.y += cs.y; acc.z += cs.z; acc.w += cs.w;
    }
    const int jb = row_ptr[node];
    const int je = row_ptr[node + 1];
    for (int j = jb; j < je; ++j) {
        int p = epack[j];
        int s = p & 0x1FFFF;
        int a = p >> 17;
        const float4 hv = *reinterpret_cast<const float4*>(h + (size_t)s * D + d0);
        const float4 ev = *reinterpret_cast<const float4*>(cee + a * D + d0);
        acc.x += hv.x + ev.x; acc.y += hv.y + ev.y;
        acc.z += hv.z + ev.z; acc.w += hv.w + ev.w;
    }
    *reinterpret_cast<float4*>(aggr + (size_t)node * D + d0) = acc;
}

// Fused MLP: out = (relu(A@W1+b1))@W2 + b2 for a 32-row block, plus
// per-column BN partial sums (sum, sumsq) reduced in LDS then one atomic each.
// NOTE: out may alias aggr — safe: the A tile is fully staged to LDS (and
// sync'd) before any global write, and blocks touch disjoint rows.
__global__ __launch_bounds__(256) void mlp_kernel(
    const float* __restrict__ aggr,
    const float* __restrict__ W1l, const float* __restrict__ b1l,
    const float* __restrict__ W2l, const float* __restrict__ b2l,
    float* __restrict__ out, float* __restrict__ stats, int n) {

    __shared__ float sA[BM * D];       // 16 KB
    __shared__ float sH[BM * TWO_D];   // 32 KB

    const int t = threadIdx.x;
    const int row0 = blockIdx.x * BM;

    #pragma unroll
    for (int i = 0; i < 4; ++i) {
        int idx = t + i * 256;          // BM*D/4 = 1024 float4
        int r  = idx >> 5;
        int c4 = (idx & 31) << 2;
        float4 v = make_float4(0.f, 0.f, 0.f, 0.f);
        if (row0 + r < n) v = *reinterpret_cast<const float4*>(aggr + (size_t)(row0 + r) * D + c4);
        *reinterpret_cast<float4*>(sA + r * D + c4) = v;
    }
    __syncthreads();

    const int tr = t >> 5;      // 0..7  -> rows r0..r0+3
    const int tc = t & 31;      // 0..31 -> cols tc*4 (+128)
    const int r0 = tr * 4;
    const int cl = tc * 4;

    // GEMM1: hid = relu(A @ W1 + b1) -> sH
    float acc[4][8];
    #pragma unroll
    for (int i = 0; i < 4; ++i)
        #pragma unroll
        for (int j = 0; j < 8; ++j) acc[i][j] = 0.f;

    #pragma unroll 4
    for (int k = 0; k < D; ++k) {
        const float4 wlo = *reinterpret_cast<const float4*>(W1l + (size_t)k * TWO_D + cl);
        const float4 whi = *reinterpret_cast<const float4*>(W1l + (size_t)k * TWO_D + cl + D);
        float a[4];
        #pragma unroll
        for (int i = 0; i < 4; ++i) a[i] = sA[(r0 + i) * D + k];
        #pragma unroll
        for (int i = 0; i < 4; ++i) {
            acc[i][0] += a[i] * wlo.x;  acc[i][1] += a[i] * wlo.y;
            acc[i][2] += a[i] * wlo.z;  acc[i][3] += a[i] * wlo.w;
            acc[i][4] += a[i] * whi.x;  acc[i][5] += a[i] * whi.y;
            acc[i][6] += a[i] * whi.z;  acc[i][7] += a[i] * whi.w;
        }
    }
    {
        const float4 blo = *reinterpret_cast<const float4*>(b1l + cl);
        const float4 bhi = *reinterpret_cast<const float4*>(b1l + cl + D);
        #pragma unroll
        for (int i = 0; i < 4; ++i) {
            float4 lo = make_float4(relu_f(acc[i][0] + blo.x), relu_f(acc[i][1] + blo.y),
                                    relu_f(acc[i][2] + blo.z), relu_f(acc[i][3] + blo.w));
            float4 hi = make_float4(relu_f(acc[i][4] + bhi.x), relu_f(acc[i][5] + bhi.y),
                                    relu_f(acc[i][6] + bhi.z), relu_f(acc[i][7] + bhi.w));
            *reinterpret_cast<float4*>(sH + (r0 + i) * TWO_D + cl)     = lo;
            *reinterpret_cast<float4*>(sH + (r0 + i) * TWO_D + cl + D) = hi;
        }
    }
    __syncthreads();

    // GEMM2: out = sH @ W2 + b2
    const int c2 = tc * 4;
    float acc2[4][4];
    #pragma unroll
    for (int i = 0; i < 4; ++i)
        #pragma unroll
        for (int j = 0; j < 4; ++j) acc2[i][j] = 0.f;

    #pragma unroll 4
    for (int k = 0; k < TWO_D; ++k) {
        const float4 w = *reinterpret_cast<const float4*>(W2l + (size_t)k * D + c2);
        #pragma unroll
        for (int i = 0; i < 4; ++i) {
            float hh = sH[(r0 + i) * TWO_D + k];
            acc2[i][0] += hh * w.x;  acc2[i][1] += hh * w.y;
            acc2[i][2] += hh * w.z;  acc2[i][3] += hh * w.w;
        }
    }

    const float4 bb = *reinterpret_cast<const float4*>(b2l + c2);
    float ps[4] = {0.f, 0.f, 0.f, 0.f};
    float pq[4] = {0.f, 0.f, 0.f, 0.f};
    #pragma unroll
    for (int i = 0; i < 4; ++i) {
        int grow = row0 + r0 + i;
        if (grow < n) {
            float4 v = make_float4(acc2[i][0] + bb.x, acc2[i][1] + bb.y,
                                   acc2[i][2] + bb.z, acc2[i][3] + bb.w);
            *reinterpret_cast<float4*>(out + (size_t)grow * D + c2) = v;
            ps[0] += v.x; ps[1] += v.y; ps[2] += v.z; ps[3] += v.w;
            pq[0] += v.x * v.x; pq[1] += v.y * v.y; pq[2] += v.z * v.z; pq[3] += v.w * v.w;
        }
    }

    __syncthreads();
    float* sRed = sA;            // 256 floats: [sum(128) | sumsq(128)]
    sRed[t] = 0.f;
    __syncthreads();
    #pragma unroll
    for (int j = 0; j < 4; ++j) {
        atomicAdd(sRed + c2 + j, ps[j]);
        atomicAdd(sRed + 128 + c2 + j, pq[j]);
    }
    __syncthreads();
    unsafeAtomicAdd(stats + t, sRed[t]);
}

// scale/shift from accumulated stats
__global__ void bn_scale_kernel(const float* __restrict__ stats,
                                const float* __restrict__ gamma_l,
                                const float* __restrict__ beta_l,
                                float* __restrict__ scsh, float inv_n) {
    int c = threadIdx.x;   // 128
    float mean = stats[c] * inv_n;
    float var  = stats[128 + c] * inv_n - mean * mean;
    float sc = gamma_l[c] * rsqrtf(var + BN_EPS);
    scsh[c]       = sc;
    scsh[128 + c] = beta_l[c] - mean * sc;
}

// dst = maybe_relu(out * scale + shift)
__global__ void bn_apply_kernel(const float* __restrict__ out,
                                const float* __restrict__ scsh,
                                float* __restrict__ dst, int n, int do_relu) {
    int idx = blockIdx.x * blockDim.x + threadIdx.x;
    int total = n * (D / 4);
    if (idx >= total) return;
    int d0 = (idx & 31) << 2;
    float4 v  = *reinterpret_cast<const float4*>(out + (size_t)idx * 4);
    float4 sc = *reinterpret_cast<const float4*>(scsh + d0);
    float4 sh = *reinterpret_cast<const float4*>(scsh + 128 + d0);
    float4 r = make_float4(v.x * sc.x + sh.x, v.y * sc.y + sh.y,
                           v.z * sc.z + sh.z, v.w * sc.w + sh.w);
    if (do_relu) r = make_float4(relu_f(r.x), relu_f(r.y), relu_f(r.z), relu_f(r.w));
    *reinterpret_cast<float4*>(dst + (size_t)idx * 4) = r;
}

extern "C" void kernel_launch(void* const* d_in, const int* in_sizes, int n_in,
                              void* d_out, int out_size, void* d_ws, size_t ws_size,
                              hipStream_t stream) {
    const int*   x     = (const int*)d_in[0];
    const int*   ei    = (const int*)d_in[1];
    const int*   ea    = (const int*)d_in[2];
    const float* aemb0 = (const float*)d_in[3];
    const float* aemb1 = (const float*)d_in[4];
    const float* eemb0 = (const float*)d_in[5];
    const float* eemb1 = (const float*)d_in[6];
    const float* W1    = (const float*)d_in[7];
    const float* b1    = (const float*)d_in[8];
    const float* W2    = (const float*)d_in[9];
    const float* b2    = (const float*)d_in[10];
    const float* gamma = (const float*)d_in[11];
    const float* beta  = (const float*)d_in[12];

    const int n = in_sizes[0] / 2;          // 50000
    const int e = in_sizes[1] / 2;          // 500000
    const int L = in_sizes[8] / TWO_D;      // 3

    // workspace layout (floats unless noted); aggr aliases outb (see mlp note)
    float* h      = (float*)d_ws;
    float* aggr   = h + (size_t)n * D;      // also used as 'out' of the MLP
    float* stats  = aggr + (size_t)n * D;   // 256: sum | sumsq
    float* scsh   = stats + 256;            // 256: scale | shift
    int*   counts = (int*)(scsh + 256);     // n
    int*   row_ptr= counts + n;             // n+1
    int*   cursor = row_ptr + n + 1;        // n
    int*   epack  = cursor + n;             // e

    const int vec_blocks = (n * (D / 4) + 255) / 256;
    const int edge_blocks = (e + 255) / 256;
    const int node_blocks = (n + 7) / 8;

    // ---- CSR build (once) ----
    hipMemsetAsync(counts, 0, (size_t)n * sizeof(int), stream);
    hist_kernel<<<edge_blocks, 256, 0, stream>>>(ei, counts, e);
    scan_kernel<<<1, 1024, 0, stream>>>(counts, row_ptr, cursor, n);
    fill_kernel<<<edge_blocks, 256, 0, stream>>>(ei, ea, cursor, epack, e);

    atom_embed_kernel<<<vec_blocks, 256, 0, stream>>>(x, aemb0, aemb1, h, n);

    for (int l = 0; l < L; ++l) {
        const float* ee0_l = eemb0 + (size_t)l * 5 * D;
        const float* ee1_l = eemb1 + (size_t)l * 3 * D;
        const float* W1l   = W1 + (size_t)l * D * TWO_D;
        const float* b1l   = b1 + (size_t)l * TWO_D;
        const float* W2l   = W2 + (size_t)l * TWO_D * D;
        const float* b2l   = b2 + (size_t)l * D;

        gather_kernel<<<node_blocks, 256, 0, stream>>>(h, ee0_l, ee1_l, row_ptr, epack,
                                                       aggr, stats, n);
        mlp_kernel<<<(n + BM - 1) / BM, 256, 0, stream>>>(aggr, W1l, b1l, W2l, b2l,
                                                          aggr, stats, n);
        bn_scale_kernel<<<1, D, 0, stream>>>(stats, gamma + (size_t)l * D, beta + (size_t)l * D,
                                             scsh, 1.0f / (float)n);
        float* dst = (l == L - 1) ? (float*)d_out : h;
        bn_apply_kernel<<<vec_blocks, 256, 0, stream>>>(aggr, scsh, dst, n, (l != L - 1) ? 1 : 0);
    }
}

// Round 3
// 426.733 us; speedup vs baseline: 7.0756x; 1.8321x over previous
//
#include <hip/hip_runtime.h>

#define D 128
#define TWO_D 256
#define BN_EPS 1e-5f

typedef __attribute__((ext_vector_type(8))) short bf16x8;   // 8 bf16 = 4 VGPR
typedef __attribute__((ext_vector_type(4))) float f32x4;

__device__ __forceinline__ float relu_f(float x) { return x > 0.f ? x : 0.f; }

__device__ __forceinline__ unsigned short f2bf(float f) {   // RTN-even
    unsigned u = __builtin_bit_cast(unsigned, f);
    return (unsigned short)((u + 0x7FFFu + ((u >> 16) & 1u)) >> 16);
}
__device__ __forceinline__ float bf2f(unsigned s) {
    unsigned u = s << 16;
    return __builtin_bit_cast(float, u);
}
__device__ __forceinline__ unsigned pack2(float a, float b) {
    return (unsigned)f2bf(a) | ((unsigned)f2bf(b) << 16);
}

// h[n][d] = bf16(atom_emb0[x0][d] + atom_emb1[x1][d])
__global__ void atom_embed_kernel(const int* __restrict__ x,
                                  const float* __restrict__ emb0,
                                  const float* __restrict__ emb1,
                                  unsigned short* __restrict__ hbf, int n) {
    int idx = blockIdx.x * blockDim.x + threadIdx.x;
    if (idx >= n * 32) return;
    int node = idx >> 5;
    int d0 = (idx & 31) << 2;
    int i0 = x[node * 2 + 0];
    int i1 = x[node * 2 + 1];
    const float4 a = *reinterpret_cast<const float4*>(emb0 + (size_t)i0 * D + d0);
    const float4 b = *reinterpret_cast<const float4*>(emb1 + (size_t)i1 * D + d0);
    uint2 v;
    v.x = pack2(a.x + b.x, a.y + b.y);
    v.y = pack2(a.z + b.z, a.w + b.w);
    *reinterpret_cast<uint2*>(hbf + (size_t)node * D + d0) = v;
}

// ---- CSR build (once per launch) ----
__global__ void hist_kernel(const int* __restrict__ ei, int* __restrict__ counts, int e_cnt) {
    int e = blockIdx.x * blockDim.x + threadIdx.x;
    if (e >= e_cnt) return;
    atomicAdd(counts + ei[e_cnt + e], 1);
}

__global__ __launch_bounds__(1024) void scan_kernel(const int* __restrict__ counts,
                                                    int* __restrict__ row_ptr,
                                                    int* __restrict__ cursor, int n) {
    __shared__ int s[1024];
    const int t = threadIdx.x;
    const int chunk = (n + 1023) / 1024;
    const int start = t * chunk;
    const int end = min(start + chunk, n);
    int sum = 0;
    for (int i = start; i < end; ++i) sum += counts[i];
    s[t] = sum;
    __syncthreads();
    for (int off = 1; off < 1024; off <<= 1) {
        int v = (t >= off) ? s[t - off] : 0;
        __syncthreads();
        s[t] += v;
        __syncthreads();
    }
    int base = (t == 0) ? 0 : s[t - 1];
    for (int i = start; i < end; ++i) {
        int c = counts[i];
        row_ptr[i] = base;
        cursor[i] = base;
        base += c;
    }
    if (t == 0) row_ptr[n] = s[1023];
}

__global__ void fill_kernel(const int* __restrict__ ei, const int* __restrict__ ea,
                            int* __restrict__ cursor, int* __restrict__ epack, int e_cnt) {
    int e = blockIdx.x * blockDim.x + threadIdx.x;
    if (e >= e_cnt) return;
    int dst = ei[e_cnt + e];
    int src = ei[e];
    int aidx = ea[e * 2 + 0] * 3 + ea[e * 2 + 1];
    int pos = atomicAdd(cursor + dst, 1);
    epack[pos] = (src & 0x1FFFF) | (aidx << 17);
}

// ---- weight fragment pre-pack (bf16, per-lane MFMA B-operand layout) ----
// w1f layout: [kk=4][tn=16][lane=64][8]; w2f: [kk2=8][tn=8][lane=64][8]
// B[k][n] for lane: n = tn*16 + (lane&15), k = kk*32 + (lane>>4)*8 + j
__global__ void frag_prep_kernel(const float* __restrict__ W1,
                                 const float* __restrict__ W2,
                                 unsigned short* __restrict__ w1f,
                                 unsigned short* __restrict__ w2f, int Lnum) {
    int tid = blockIdx.x * blockDim.x + threadIdx.x;
    if (tid >= Lnum * 128 * 64) return;
    int l = tid / 8192;
    int rem = tid % 8192;
    int frag = rem / 64;
    int lane = rem % 64;
    int kg = lane >> 4, cl = lane & 15;
    if (frag < 64) {
        int kk = frag >> 4, tn = frag & 15;
        const float* src = W1 + (size_t)l * D * TWO_D;
        int k0 = kk * 32 + kg * 8, col = tn * 16 + cl;
        unsigned short* dst = w1f + (size_t)l * 32768 + ((size_t)frag * 64 + lane) * 8;
        #pragma unroll
        for (int j = 0; j < 8; ++j) dst[j] = f2bf(src[(size_t)(k0 + j) * TWO_D + col]);
    } else {
        int f2 = frag - 64;
        int kk = f2 >> 3, tn = f2 & 7;
        const float* src = W2 + (size_t)l * TWO_D * D;
        int k0 = kk * 32 + kg * 8, col = tn * 16 + cl;
        unsigned short* dst = w2f + (size_t)l * 32768 + ((size_t)f2 * 64 + lane) * 8;
        #pragma unroll
        for (int j = 0; j < 8; ++j) dst[j] = f2bf(src[(size_t)(k0 + j) * D + col]);
    }
}

// ---- gather over CSR (bf16 h in, bf16 aggr out, f32 accumulate) ----
__global__ __launch_bounds__(256) void gather_kernel(
    const unsigned short* __restrict__ hbf,
    const float* __restrict__ ee0_l, const float* __restrict__ ee1_l,
    const int* __restrict__ row_ptr, const int* __restrict__ epack,
    unsigned short* __restrict__ aggrbf, float* __restrict__ stats, int n) {

    __shared__ float cee[16 * D];
    const int t = threadIdx.x;
    if (blockIdx.x == 0) stats[t] = 0.f;
    for (int i = t; i < 16 * D; i += 256) {
        int r = i >> 7, d = i & 127;
        cee[i] = (r < 15) ? ee0_l[(r / 3) * D + d] + ee1_l[(r % 3) * D + d]
                          : ee0_l[4 * D + d] + ee1_l[d];
    }
    __syncthreads();
    int node = blockIdx.x * 8 + (t >> 5);
    if (node >= n) return;
    int d0 = (t & 31) << 2;

    uint2 hv = *reinterpret_cast<const uint2*>(hbf + (size_t)node * D + d0);
    float4 cs = *reinterpret_cast<const float4*>(cee + 15 * D + d0);
    float ax = bf2f(hv.x & 0xffffu) + cs.x;
    float ay = bf2f(hv.x >> 16)     + cs.y;
    float az = bf2f(hv.y & 0xffffu) + cs.z;
    float aw = bf2f(hv.y >> 16)     + cs.w;

    const int jb = row_ptr[node];
    const int je = row_ptr[node + 1];
    for (int j = jb; j < je; ++j) {
        int p = epack[j];
        int s = p & 0x1FFFF;
        int a = p >> 17;
        uint2 sv = *reinterpret_cast<const uint2*>(hbf + (size_t)s * D + d0);
        float4 ev = *reinterpret_cast<const float4*>(cee + a * D + d0);
        ax += bf2f(sv.x & 0xffffu) + ev.x;
        ay += bf2f(sv.x >> 16)     + ev.y;
        az += bf2f(sv.y & 0xffffu) + ev.z;
        aw += bf2f(sv.y >> 16)     + ev.w;
    }
    uint2 o;
    o.x = pack2(ax, ay);
    o.y = pack2(az, aw);
    *reinterpret_cast<uint2*>(aggrbf + (size_t)node * D + d0) = o;
}

// ---- MFMA fused MLP: out = relu(A@W1+b1)@W2 + b2, BN partial sums ----
// 4 waves; wave w owns hid cols [64w,64w+64) and out cols [32w,32w+32).
// Weight frags register-resident; hid transposed through XOR-swizzled LDS.
__global__ __launch_bounds__(256) void mlp_mfma_kernel(
    const unsigned short* __restrict__ aggrbf,
    const bf16x8* __restrict__ w1f, const bf16x8* __restrict__ w2f,
    const float* __restrict__ b1l, const float* __restrict__ b2l,
    float* __restrict__ out, float* __restrict__ stats, int n) {

    __shared__ unsigned short hid[16 * TWO_D];   // 8 KB, XOR-swizzled
    __shared__ float sred[256];

    const int wave = threadIdx.x >> 6;
    const int lane = threadIdx.x & 63;
    const int arow = lane & 15;     // A row / C-D col within 16x16 tile
    const int kgrp = lane >> 4;     // k-group: k = 8*kgrp + j; C-D rows 4*kgrp+r

    bf16x8 W1[4][4];
    #pragma unroll
    for (int kk = 0; kk < 4; ++kk)
        #pragma unroll
        for (int t = 0; t < 4; ++t)
            W1[kk][t] = w1f[(kk * 16 + wave * 4 + t) * 64 + lane];
    bf16x8 W2[8][2];
    #pragma unroll
    for (int kk = 0; kk < 8; ++kk)
        #pragma unroll
        for (int t = 0; t < 2; ++t)
            W2[kk][t] = w2f[(kk * 8 + wave * 2 + t) * 64 + lane];

    float b1v[4], b2v[2];
    #pragma unroll
    for (int t = 0; t < 4; ++t) b1v[t] = b1l[wave * 64 + t * 16 + arow];
    #pragma unroll
    for (int t = 0; t < 2; ++t) b2v[t] = b2l[wave * 32 + t * 16 + arow];

    float ps[2] = {0.f, 0.f}, pq[2] = {0.f, 0.f};

    const int tiles = n >> 4;       // n % 16 == 0 (50000)
    for (int tile = blockIdx.x; tile < tiles; tile += gridDim.x) {
        const size_t row0 = (size_t)tile * 16;

        bf16x8 a[4];
        #pragma unroll
        for (int kk = 0; kk < 4; ++kk)
            a[kk] = *reinterpret_cast<const bf16x8*>(
                aggrbf + (row0 + arow) * D + kk * 32 + kgrp * 8);

        f32x4 acc1[4];
        #pragma unroll
        for (int t = 0; t < 4; ++t) acc1[t] = (f32x4){0.f, 0.f, 0.f, 0.f};
        #pragma unroll
        for (int kk = 0; kk < 4; ++kk)
            #pragma unroll
            for (int t = 0; t < 4; ++t)
                acc1[t] = __builtin_amdgcn_mfma_f32_16x16x32_bf16(a[kk], W1[kk][t], acc1[t], 0, 0, 0);

        __syncthreads();   // protect hid reads of previous iteration
        #pragma unroll
        for (int t = 0; t < 4; ++t) {
            const int cc = wave * 64 + t * 16 + arow;
            #pragma unroll
            for (int r = 0; r < 4; ++r) {
                const int rr = kgrp * 4 + r;
                float v = relu_f(acc1[t][r] + b1v[t]);
                hid[(rr * TWO_D + cc) ^ ((rr & 7) << 3)] = f2bf(v);
            }
        }
        __syncthreads();

        f32x4 acc2[2];
        #pragma unroll
        for (int t = 0; t < 2; ++t) acc2[t] = (f32x4){0.f, 0.f, 0.f, 0.f};
        #pragma unroll
        for (int kk = 0; kk < 8; ++kk) {
            bf16x8 a2 = *reinterpret_cast<const bf16x8*>(
                hid + ((arow * TWO_D + kk * 32 + kgrp * 8) ^ ((arow & 7) << 3)));
            #pragma unroll
            for (int t = 0; t < 2; ++t)
                acc2[t] = __builtin_amdgcn_mfma_f32_16x16x32_bf16(a2, W2[kk][t], acc2[t], 0, 0, 0);
        }

        #pragma unroll
        for (int t = 0; t < 2; ++t) {
            const int col = wave * 32 + t * 16 + arow;
            #pragma unroll
            for (int r = 0; r < 4; ++r) {
                float v = acc2[t][r] + b2v[t];
                out[(row0 + kgrp * 4 + r) * D + col] = v;
                ps[t] += v;
                pq[t] += v * v;
            }
        }
    }

    sred[threadIdx.x] = 0.f;
    __syncthreads();
    #pragma unroll
    for (int t = 0; t < 2; ++t) {
        const int col = wave * 32 + t * 16 + arow;
        atomicAdd(sred + col, ps[t]);
        atomicAdd(sred + 128 + col, pq[t]);
    }
    __syncthreads();
    unsafeAtomicAdd(stats + threadIdx.x, sred[threadIdx.x]);
}

__global__ void bn_scale_kernel(const float* __restrict__ stats,
                                const float* __restrict__ gamma_l,
                                const float* __restrict__ beta_l,
                                float* __restrict__ scsh, float inv_n) {
    int c = threadIdx.x;   // 128
    float mean = stats[c] * inv_n;
    float var  = stats[128 + c] * inv_n - mean * mean;
    float sc = gamma_l[c] * rsqrtf(var + BN_EPS);
    scsh[c]       = sc;
    scsh[128 + c] = beta_l[c] - mean * sc;
}

// intermediate layers: h = bf16(relu(out*sc+sh))
__global__ void bn_apply_mid_kernel(const float* __restrict__ out,
                                    const float* __restrict__ scsh,
                                    unsigned short* __restrict__ hbf, int n) {
    int idx = blockIdx.x * blockDim.x + threadIdx.x;
    if (idx >= n * 32) return;
    int d0 = (idx & 31) << 2;
    float4 v  = *reinterpret_cast<const float4*>(out + (size_t)idx * 4);
    float4 sc = *reinterpret_cast<const float4*>(scsh + d0);
    float4 sh = *reinterpret_cast<const float4*>(scsh + 128 + d0);
    uint2 o;
    o.x = pack2(relu_f(v.x * sc.x + sh.x), relu_f(v.y * sc.y + sh.y));
    o.y = pack2(relu_f(v.z * sc.z + sh.z), relu_f(v.w * sc.w + sh.w));
    *reinterpret_cast<uint2*>(hbf + (size_t)idx * 4) = o;
}

// final layer: d_out = out*sc+sh (f32, no relu)
__global__ void bn_apply_final_kernel(const float* __restrict__ out,
                                      const float* __restrict__ scsh,
                                      float* __restrict__ dst, int n) {
    int idx = blockIdx.x * blockDim.x + threadIdx.x;
    if (idx >= n * 32) return;
    int d0 = (idx & 31) << 2;
    float4 v  = *reinterpret_cast<const float4*>(out + (size_t)idx * 4);
    float4 sc = *reinterpret_cast<const float4*>(scsh + d0);
    float4 sh = *reinterpret_cast<const float4*>(scsh + 128 + d0);
    *reinterpret_cast<float4*>(dst + (size_t)idx * 4) =
        make_float4(v.x * sc.x + sh.x, v.y * sc.y + sh.y,
                    v.z * sc.z + sh.z, v.w * sc.w + sh.w);
}

extern "C" void kernel_launch(void* const* d_in, const int* in_sizes, int n_in,
                              void* d_out, int out_size, void* d_ws, size_t ws_size,
                              hipStream_t stream) {
    const int*   x     = (const int*)d_in[0];
    const int*   ei    = (const int*)d_in[1];
    const int*   ea    = (const int*)d_in[2];
    const float* aemb0 = (const float*)d_in[3];
    const float* aemb1 = (const float*)d_in[4];
    const float* eemb0 = (const float*)d_in[5];
    const float* eemb1 = (const float*)d_in[6];
    const float* W1    = (const float*)d_in[7];
    const float* b1    = (const float*)d_in[8];
    const float* W2    = (const float*)d_in[9];
    const float* b2    = (const float*)d_in[10];
    const float* gamma = (const float*)d_in[11];
    const float* beta  = (const float*)d_in[12];

    const int n = in_sizes[0] / 2;          // 50000
    const int e = in_sizes[1] / 2;          // 500000
    const int L = in_sizes[8] / TWO_D;      // 3

    char* ws = (char*)d_ws;
    float* outb = (float*)ws;                      ws += (size_t)n * D * 4;
    unsigned short* hbf = (unsigned short*)ws;     ws += (size_t)n * D * 2;
    unsigned short* aggrbf = (unsigned short*)ws;  ws += (size_t)n * D * 2;
    unsigned short* w1f = (unsigned short*)ws;     ws += (size_t)L * 32768 * 2;
    unsigned short* w2f = (unsigned short*)ws;     ws += (size_t)L * 32768 * 2;
    float* stats = (float*)ws;                     ws += 256 * 4;
    float* scsh  = (float*)ws;                     ws += 256 * 4;
    int* counts  = (int*)ws;                       ws += (size_t)n * 4;
    int* row_ptr = (int*)ws;                       ws += (size_t)(n + 1) * 4;
    int* cursor  = (int*)ws;                       ws += (size_t)n * 4;
    int* epack   = (int*)ws;

    const int edge_blocks = (e + 255) / 256;
    const int vec_blocks  = (n * 32 + 255) / 256;
    const int node_blocks = (n + 7) / 8;

    hipMemsetAsync(counts, 0, (size_t)n * sizeof(int), stream);
    hist_kernel<<<edge_blocks, 256, 0, stream>>>(ei, counts, e);
    scan_kernel<<<1, 1024, 0, stream>>>(counts, row_ptr, cursor, n);
    fill_kernel<<<edge_blocks, 256, 0, stream>>>(ei, ea, cursor, epack, e);
    frag_prep_kernel<<<(L * 128 * 64 + 255) / 256, 256, 0, stream>>>(W1, W2, w1f, w2f, L);
    atom_embed_kernel<<<vec_blocks, 256, 0, stream>>>(x, aemb0, aemb1, hbf, n);

    for (int l = 0; l < L; ++l) {
        const float* ee0_l = eemb0 + (size_t)l * 5 * D;
        const float* ee1_l = eemb1 + (size_t)l * 3 * D;
        const float* b1l   = b1 + (size_t)l * TWO_D;
        const float* b2l   = b2 + (size_t)l * D;

        gather_kernel<<<node_blocks, 256, 0, stream>>>(hbf, ee0_l, ee1_l, row_ptr, epack,
                                                       aggrbf, stats, n);
        mlp_mfma_kernel<<<512, 256, 0, stream>>>(
            aggrbf,
            (const bf16x8*)(w1f + (size_t)l * 32768),
            (const bf16x8*)(w2f + (size_t)l * 32768),
            b1l, b2l, outb, stats, n);
        bn_scale_kernel<<<1, D, 0, stream>>>(stats, gamma + (size_t)l * D, beta + (size_t)l * D,
                                             scsh, 1.0f / (float)n);
        if (l == L - 1)
            bn_apply_final_kernel<<<vec_blocks, 256, 0, stream>>>(outb, scsh, (float*)d_out, n);
        else
            bn_apply_mid_kernel<<<vec_blocks, 256, 0, stream>>>(outb, scsh, hbf, n);
    }
}

// Round 4
// 316.629 us; speedup vs baseline: 9.5360x; 1.3477x over previous
//
#include <hip/hip_runtime.h>

#define D 128
#define TWO_D 256
#define BN_EPS 1e-5f

typedef __attribute__((ext_vector_type(8))) short bf16x8;   // 8 bf16 = 4 VGPR
typedef __attribute__((ext_vector_type(4))) float f32x4;

__device__ __forceinline__ float relu_f(float x) { return x > 0.f ? x : 0.f; }

__device__ __forceinline__ unsigned short f2bf(float f) {   // RTN-even
    unsigned u = __builtin_bit_cast(unsigned, f);
    return (unsigned short)((u + 0x7FFFu + ((u >> 16) & 1u)) >> 16);
}
__device__ __forceinline__ float bf2f(unsigned s) {
    unsigned u = s << 16;
    return __builtin_bit_cast(float, u);
}
__device__ __forceinline__ unsigned pack2(float a, float b) {
    return (unsigned)f2bf(a) | ((unsigned)f2bf(b) << 16);
}

// h[n][d] = bf16(atom_emb0[x0][d] + atom_emb1[x1][d])
__global__ void atom_embed_kernel(const int* __restrict__ x,
                                  const float* __restrict__ emb0,
                                  const float* __restrict__ emb1,
                                  unsigned short* __restrict__ hbf, int n) {
    int idx = blockIdx.x * blockDim.x + threadIdx.x;
    if (idx >= n * 32) return;
    int node = idx >> 5;
    int d0 = (idx & 31) << 2;
    int i0 = x[node * 2 + 0];
    int i1 = x[node * 2 + 1];
    const float4 a = *reinterpret_cast<const float4*>(emb0 + (size_t)i0 * D + d0);
    const float4 b = *reinterpret_cast<const float4*>(emb1 + (size_t)i1 * D + d0);
    uint2 v;
    v.x = pack2(a.x + b.x, a.y + b.y);
    v.y = pack2(a.z + b.z, a.w + b.w);
    *reinterpret_cast<uint2*>(hbf + (size_t)node * D + d0) = v;
}

// ---- CSR build (once per launch) ----
__global__ void hist_kernel(const int* __restrict__ ei, int* __restrict__ counts, int e_cnt) {
    int e = blockIdx.x * blockDim.x + threadIdx.x;
    if (e >= e_cnt) return;
    atomicAdd(counts + ei[e_cnt + e], 1);
}

// stage 1: per-block (256 elems) sums
__global__ __launch_bounds__(256) void bsum_kernel(const int* __restrict__ counts,
                                                   int* __restrict__ bsum, int n) {
    __shared__ int s[256];
    int t = threadIdx.x;
    int idx = blockIdx.x * 256 + t;
    s[t] = (idx < n) ? counts[idx] : 0;
    __syncthreads();
    for (int off = 128; off > 0; off >>= 1) {
        if (t < off) s[t] += s[t + off];
        __syncthreads();
    }
    if (t == 0) bsum[blockIdx.x] = s[0];
}

// stage 2: single-block exclusive scan of <=256 block sums; also row_ptr[n]=total
__global__ __launch_bounds__(256) void bscan_kernel(const int* __restrict__ bsum,
                                                    int* __restrict__ bpre,
                                                    int* __restrict__ row_ptr, int nb, int n) {
    __shared__ int s[256];
    int t = threadIdx.x;
    s[t] = (t < nb) ? bsum[t] : 0;
    __syncthreads();
    for (int off = 1; off < 256; off <<= 1) {
        int v = (t >= off) ? s[t - off] : 0;
        __syncthreads();
        s[t] += v;
        __syncthreads();
    }
    bpre[t] = (t == 0) ? 0 : s[t - 1];
    if (t == 255) row_ptr[n] = s[255];
}

// stage 3: block-local exclusive scan + block prefix -> row_ptr, cursor
__global__ __launch_bounds__(256) void scan_apply_kernel(const int* __restrict__ counts,
                                                         const int* __restrict__ bpre,
                                                         int* __restrict__ row_ptr,
                                                         int* __restrict__ cursor, int n) {
    __shared__ int s[256];
    int t = threadIdx.x;
    int idx = blockIdx.x * 256 + t;
    int c = (idx < n) ? counts[idx] : 0;
    s[t] = c;
    __syncthreads();
    for (int off = 1; off < 256; off <<= 1) {
        int v = (t >= off) ? s[t - off] : 0;
        __syncthreads();
        s[t] += v;
        __syncthreads();
    }
    if (idx < n) {
        int excl = bpre[blockIdx.x] + s[t] - c;
        row_ptr[idx] = excl;
        cursor[idx] = excl;
    }
}

__global__ void fill_kernel(const int* __restrict__ ei, const int* __restrict__ ea,
                            int* __restrict__ cursor, int* __restrict__ epack, int e_cnt) {
    int e = blockIdx.x * blockDim.x + threadIdx.x;
    if (e >= e_cnt) return;
    int dst = ei[e_cnt + e];
    int src = ei[e];
    int aidx = ea[e * 2 + 0] * 3 + ea[e * 2 + 1];
    int pos = atomicAdd(cursor + dst, 1);
    epack[pos] = (src & 0x1FFFF) | (aidx << 17);
}

// ---- weight fragment pre-pack (bf16, per-lane MFMA B-operand layout) ----
__global__ void frag_prep_kernel(const float* __restrict__ W1,
                                 const float* __restrict__ W2,
                                 unsigned short* __restrict__ w1f,
                                 unsigned short* __restrict__ w2f, int Lnum) {
    int tid = blockIdx.x * blockDim.x + threadIdx.x;
    if (tid >= Lnum * 128 * 64) return;
    int l = tid / 8192;
    int rem = tid % 8192;
    int frag = rem / 64;
    int lane = rem % 64;
    int kg = lane >> 4, cl = lane & 15;
    if (frag < 64) {
        int kk = frag >> 4, tn = frag & 15;
        const float* src = W1 + (size_t)l * D * TWO_D;
        int k0 = kk * 32 + kg * 8, col = tn * 16 + cl;
        unsigned short* dst = w1f + (size_t)l * 32768 + ((size_t)frag * 64 + lane) * 8;
        #pragma unroll
        for (int j = 0; j < 8; ++j) dst[j] = f2bf(src[(size_t)(k0 + j) * TWO_D + col]);
    } else {
        int f2 = frag - 64;
        int kk = f2 >> 3, tn = f2 & 7;
        const float* src = W2 + (size_t)l * TWO_D * D;
        int k0 = kk * 32 + kg * 8, col = tn * 16 + cl;
        unsigned short* dst = w2f + (size_t)l * 32768 + ((size_t)f2 * 64 + lane) * 8;
        #pragma unroll
        for (int j = 0; j < 8; ++j) dst[j] = f2bf(src[(size_t)(k0 + j) * D + col]);
    }
}

// ---- gather over CSR with optional fused BN+ReLU of the SOURCE values ----
// src values are raw bf16; if do_bn, each element v -> relu(v*sc[d]+sh[d])
// aggr[v] = xform(h[v]) + cee[self] + sum_edges (xform(h[src]) + cee[aidx])
__global__ __launch_bounds__(256) void gather_kernel(
    const unsigned short* __restrict__ hbf,
    const float* __restrict__ ee0_l, const float* __restrict__ ee1_l,
    const float* __restrict__ scsh,
    const int* __restrict__ row_ptr, const int* __restrict__ epack,
    unsigned short* __restrict__ aggrbf, float* __restrict__ stats,
    int n, int do_bn) {

    __shared__ float cee[16 * D];
    const int t = threadIdx.x;
    if (blockIdx.x == 0) stats[t] = 0.f;
    for (int i = t; i < 16 * D; i += 256) {
        int r = i >> 7, d = i & 127;
        cee[i] = (r < 15) ? ee0_l[(r / 3) * D + d] + ee1_l[(r % 3) * D + d]
                          : ee0_l[4 * D + d] + ee1_l[d];
    }
    __syncthreads();
    int node = blockIdx.x * 8 + (t >> 5);
    if (node >= n) return;
    int d0 = (t & 31) << 2;

    const int jb = row_ptr[node];
    const int je = row_ptr[node + 1];
    float4 cs = *reinterpret_cast<const float4*>(cee + 15 * D + d0);
    float ax, ay, az, aw;

    if (do_bn) {
        const float4 sc = *reinterpret_cast<const float4*>(scsh + d0);
        const float4 sh = *reinterpret_cast<const float4*>(scsh + 128 + d0);
        uint2 hv = *reinterpret_cast<const uint2*>(hbf + (size_t)node * D + d0);
        ax = relu_f(bf2f(hv.x & 0xffffu) * sc.x + sh.x) + cs.x;
        ay = relu_f(bf2f(hv.x >> 16)     * sc.y + sh.y) + cs.y;
        az = relu_f(bf2f(hv.y & 0xffffu) * sc.z + sh.z) + cs.z;
        aw = relu_f(bf2f(hv.y >> 16)     * sc.w + sh.w) + cs.w;
        for (int j = jb; j < je; ++j) {
            int p = epack[j];
            int s = p & 0x1FFFF;
            int a = p >> 17;
            uint2 sv = *reinterpret_cast<const uint2*>(hbf + (size_t)s * D + d0);
            float4 ev = *reinterpret_cast<const float4*>(cee + a * D + d0);
            ax += relu_f(bf2f(sv.x & 0xffffu) * sc.x + sh.x) + ev.x;
            ay += relu_f(bf2f(sv.x >> 16)     * sc.y + sh.y) + ev.y;
            az += relu_f(bf2f(sv.y & 0xffffu) * sc.z + sh.z) + ev.z;
            aw += relu_f(bf2f(sv.y >> 16)     * sc.w + sh.w) + ev.w;
        }
    } else {
        uint2 hv = *reinterpret_cast<const uint2*>(hbf + (size_t)node * D + d0);
        ax = bf2f(hv.x & 0xffffu) + cs.x;
        ay = bf2f(hv.x >> 16)     + cs.y;
        az = bf2f(hv.y & 0xffffu) + cs.z;
        aw = bf2f(hv.y >> 16)     + cs.w;
        for (int j = jb; j < je; ++j) {
            int p = epack[j];
            int s = p & 0x1FFFF;
            int a = p >> 17;
            uint2 sv = *reinterpret_cast<const uint2*>(hbf + (size_t)s * D + d0);
            float4 ev = *reinterpret_cast<const float4*>(cee + a * D + d0);
            ax += bf2f(sv.x & 0xffffu) + ev.x;
            ay += bf2f(sv.x >> 16)     + ev.y;
            az += bf2f(sv.y & 0xffffu) + ev.z;
            aw += bf2f(sv.y >> 16)     + ev.w;
        }
    }
    uint2 o;
    o.x = pack2(ax, ay);
    o.y = pack2(az, aw);
    *reinterpret_cast<uint2*>(aggrbf + (size_t)node * D + d0) = o;
}

// ---- MFMA fused MLP: out = relu(A@W1+b1)@W2 + b2, BN partial sums ----
// If final_f32: write f32 to outf; else write bf16 IN-PLACE to aggrbf (safe:
// all A-frag reads happen before the first __syncthreads; writes after the
// second; tiles are disjoint across blocks).
__global__ __launch_bounds__(256) void mlp_mfma_kernel(
    unsigned short* __restrict__ aggrbf,
    const bf16x8* __restrict__ w1f, const bf16x8* __restrict__ w2f,
    const float* __restrict__ b1l, const float* __restrict__ b2l,
    float* __restrict__ outf, float* __restrict__ stats, int n, int final_f32) {

    __shared__ unsigned short hid[16 * TWO_D];   // 8 KB, XOR-swizzled
    __shared__ float sred[256];

    const int wave = threadIdx.x >> 6;
    const int lane = threadIdx.x & 63;
    const int arow = lane & 15;
    const int kgrp = lane >> 4;

    bf16x8 W1[4][4];
    #pragma unroll
    for (int kk = 0; kk < 4; ++kk)
        #pragma unroll
        for (int t = 0; t < 4; ++t)
            W1[kk][t] = w1f[(kk * 16 + wave * 4 + t) * 64 + lane];
    bf16x8 W2[8][2];
    #pragma unroll
    for (int kk = 0; kk < 8; ++kk)
        #pragma unroll
        for (int t = 0; t < 2; ++t)
            W2[kk][t] = w2f[(kk * 8 + wave * 2 + t) * 64 + lane];

    float b1v[4], b2v[2];
    #pragma unroll
    for (int t = 0; t < 4; ++t) b1v[t] = b1l[wave * 64 + t * 16 + arow];
    #pragma unroll
    for (int t = 0; t < 2; ++t) b2v[t] = b2l[wave * 32 + t * 16 + arow];

    float ps[2] = {0.f, 0.f}, pq[2] = {0.f, 0.f};

    const int tiles = n >> 4;       // n % 16 == 0
    for (int tile = blockIdx.x; tile < tiles; tile += gridDim.x) {
        const size_t row0 = (size_t)tile * 16;

        bf16x8 a[4];
        #pragma unroll
        for (int kk = 0; kk < 4; ++kk)
            a[kk] = *reinterpret_cast<const bf16x8*>(
                aggrbf + (row0 + arow) * D + kk * 32 + kgrp * 8);

        f32x4 acc1[4];
        #pragma unroll
        for (int t = 0; t < 4; ++t) acc1[t] = (f32x4){0.f, 0.f, 0.f, 0.f};
        #pragma unroll
        for (int kk = 0; kk < 4; ++kk)
            #pragma unroll
            for (int t = 0; t < 4; ++t)
                acc1[t] = __builtin_amdgcn_mfma_f32_16x16x32_bf16(a[kk], W1[kk][t], acc1[t], 0, 0, 0);

        __syncthreads();   // protect hid reads of previous iteration
        #pragma unroll
        for (int t = 0; t < 4; ++t) {
            const int cc = wave * 64 + t * 16 + arow;
            #pragma unroll
            for (int r = 0; r < 4; ++r) {
                const int rr = kgrp * 4 + r;
                float v = relu_f(acc1[t][r] + b1v[t]);
                hid[(rr * TWO_D + cc) ^ ((rr & 7) << 3)] = f2bf(v);
            }
        }
        __syncthreads();

        f32x4 acc2[2];
        #pragma unroll
        for (int t = 0; t < 2; ++t) acc2[t] = (f32x4){0.f, 0.f, 0.f, 0.f};
        #pragma unroll
        for (int kk = 0; kk < 8; ++kk) {
            bf16x8 a2 = *reinterpret_cast<const bf16x8*>(
                hid + ((arow * TWO_D + kk * 32 + kgrp * 8) ^ ((arow & 7) << 3)));
            #pragma unroll
            for (int t = 0; t < 2; ++t)
                acc2[t] = __builtin_amdgcn_mfma_f32_16x16x32_bf16(a2, W2[kk][t], acc2[t], 0, 0, 0);
        }

        if (final_f32) {
            #pragma unroll
            for (int t = 0; t < 2; ++t) {
                const int col = wave * 32 + t * 16 + arow;
                #pragma unroll
                for (int r = 0; r < 4; ++r) {
                    float v = acc2[t][r] + b2v[t];
                    outf[(row0 + kgrp * 4 + r) * D + col] = v;
                    ps[t] += v; pq[t] += v * v;
                }
            }
        } else {
            #pragma unroll
            for (int t = 0; t < 2; ++t) {
                const int col = wave * 32 + t * 16 + arow;
                #pragma unroll
                for (int r = 0; r < 4; ++r) {
                    float v = acc2[t][r] + b2v[t];
                    aggrbf[(row0 + kgrp * 4 + r) * D + col] = f2bf(v);
                    ps[t] += v; pq[t] += v * v;
                }
            }
        }
    }

    sred[threadIdx.x] = 0.f;
    __syncthreads();
    #pragma unroll
    for (int t = 0; t < 2; ++t) {
        const int col = wave * 32 + t * 16 + arow;
        atomicAdd(sred + col, ps[t]);
        atomicAdd(sred + 128 + col, pq[t]);
    }
    __syncthreads();
    unsafeAtomicAdd(stats + threadIdx.x, sred[threadIdx.x]);
}

__global__ void bn_scale_kernel(const float* __restrict__ stats,
                                const float* __restrict__ gamma_l,
                                const float* __restrict__ beta_l,
                                float* __restrict__ scsh, float inv_n) {
    int c = threadIdx.x;   // 128
    float mean = stats[c] * inv_n;
    float var  = stats[128 + c] * inv_n - mean * mean;
    float sc = gamma_l[c] * rsqrtf(var + BN_EPS);
    scsh[c]       = sc;
    scsh[128 + c] = beta_l[c] - mean * sc;
}

// final layer: d_out = out*sc+sh (f32, no relu)
__global__ void bn_apply_final_kernel(const float* __restrict__ out,
                                      const float* __restrict__ scsh,
                                      float* __restrict__ dst, int n) {
    int idx = blockIdx.x * blockDim.x + threadIdx.x;
    if (idx >= n * 32) return;
    int d0 = (idx & 31) << 2;
    float4 v  = *reinterpret_cast<const float4*>(out + (size_t)idx * 4);
    float4 sc = *reinterpret_cast<const float4*>(scsh + d0);
    float4 sh = *reinterpret_cast<const float4*>(scsh + 128 + d0);
    *reinterpret_cast<float4*>(dst + (size_t)idx * 4) =
        make_float4(v.x * sc.x + sh.x, v.y * sc.y + sh.y,
                    v.z * sc.z + sh.z, v.w * sc.w + sh.w);
}

extern "C" void kernel_launch(void* const* d_in, const int* in_sizes, int n_in,
                              void* d_out, int out_size, void* d_ws, size_t ws_size,
                              hipStream_t stream) {
    const int*   x     = (const int*)d_in[0];
    const int*   ei    = (const int*)d_in[1];
    const int*   ea    = (const int*)d_in[2];
    const float* aemb0 = (const float*)d_in[3];
    const float* aemb1 = (const float*)d_in[4];
    const float* eemb0 = (const float*)d_in[5];
    const float* eemb1 = (const float*)d_in[6];
    const float* W1    = (const float*)d_in[7];
    const float* b1    = (const float*)d_in[8];
    const float* W2    = (const float*)d_in[9];
    const float* b2    = (const float*)d_in[10];
    const float* gamma = (const float*)d_in[11];
    const float* beta  = (const float*)d_in[12];

    const int n = in_sizes[0] / 2;          // 50000
    const int e = in_sizes[1] / 2;          // 500000
    const int L = in_sizes[8] / TWO_D;      // 3

    char* ws = (char*)d_ws;
    float* outb = (float*)ws;                      ws += (size_t)n * D * 4;
    unsigned short* bufA = (unsigned short*)ws;    ws += (size_t)n * D * 2;
    unsigned short* bufB = (unsigned short*)ws;    ws += (size_t)n * D * 2;
    unsigned short* w1f = (unsigned short*)ws;     ws += (size_t)L * 32768 * 2;
    unsigned short* w2f = (unsigned short*)ws;     ws += (size_t)L * 32768 * 2;
    float* stats = (float*)ws;                     ws += 256 * 4;
    float* scsh  = (float*)ws;                     ws += 256 * 4;
    int* counts  = (int*)ws;                       ws += (size_t)n * 4;
    int* row_ptr = (int*)ws;                       ws += (size_t)(n + 1) * 4;
    int* cursor  = (int*)ws;                       ws += (size_t)n * 4;
    int* bsum    = (int*)ws;                       ws += 256 * 4;
    int* bpre    = (int*)ws;                       ws += 256 * 4;
    int* epack   = (int*)ws;

    const int edge_blocks = (e + 255) / 256;
    const int vec_blocks  = (n * 32 + 255) / 256;
    const int node_blocks = (n + 7) / 8;
    const int nb = (n + 255) / 256;          // 196 <= 256

    hipMemsetAsync(counts, 0, (size_t)n * sizeof(int), stream);
    hist_kernel<<<edge_blocks, 256, 0, stream>>>(ei, counts, e);
    bsum_kernel<<<nb, 256, 0, stream>>>(counts, bsum, n);
    bscan_kernel<<<1, 256, 0, stream>>>(bsum, bpre, row_ptr, nb, n);
    scan_apply_kernel<<<nb, 256, 0, stream>>>(counts, bpre, row_ptr, cursor, n);
    fill_kernel<<<edge_blocks, 256, 0, stream>>>(ei, ea, cursor, epack, e);
    frag_prep_kernel<<<(L * 128 * 64 + 255) / 256, 256, 0, stream>>>(W1, W2, w1f, w2f, L);
    atom_embed_kernel<<<vec_blocks, 256, 0, stream>>>(x, aemb0, aemb1, bufA, n);

    for (int l = 0; l < L; ++l) {
        const float* ee0_l = eemb0 + (size_t)l * 5 * D;
        const float* ee1_l = eemb1 + (size_t)l * 3 * D;
        const float* b1l   = b1 + (size_t)l * TWO_D;
        const float* b2l   = b2 + (size_t)l * D;

        unsigned short* src = (l & 1) ? bufB : bufA;   // previous layer's values
        unsigned short* dst = (l & 1) ? bufA : bufB;   // gather out + mlp in/out

        gather_kernel<<<node_blocks, 256, 0, stream>>>(src, ee0_l, ee1_l, scsh,
                                                       row_ptr, epack, dst, stats,
                                                       n, (l > 0) ? 1 : 0);
        mlp_mfma_kernel<<<512, 256, 0, stream>>>(
            dst,
            (const bf16x8*)(w1f + (size_t)l * 32768),
            (const bf16x8*)(w2f + (size_t)l * 32768),
            b1l, b2l, outb, stats, n, (l == L - 1) ? 1 : 0);
        bn_scale_kernel<<<1, D, 0, stream>>>(stats, gamma + (size_t)l * D, beta + (size_t)l * D,
                                             scsh, 1.0f / (float)n);
    }
    bn_apply_final_kernel<<<vec_blocks, 256, 0, stream>>>(outb, scsh, (float*)d_out, n);
}

// Round 5
// 296.951 us; speedup vs baseline: 10.1679x; 1.0663x over previous
//
#include <hip/hip_runtime.h>

#define D 128
#define TWO_D 256
#define BN_EPS 1e-5f

typedef __attribute__((ext_vector_type(8))) short bf16x8;   // 8 bf16 = 4 VGPR
typedef __attribute__((ext_vector_type(4))) float f32x4;

__device__ __forceinline__ float relu_f(float x) { return x > 0.f ? x : 0.f; }

__device__ __forceinline__ unsigned short f2bf(float f) {   // RTN-even
    unsigned u = __builtin_bit_cast(unsigned, f);
    return (unsigned short)((u + 0x7FFFu + ((u >> 16) & 1u)) >> 16);
}
__device__ __forceinline__ float bf2f(unsigned s) {
    unsigned u = s << 16;
    return __builtin_bit_cast(float, u);
}
__device__ __forceinline__ unsigned pack2(float a, float b) {
    return (unsigned)f2bf(a) | ((unsigned)f2bf(b) << 16);
}

// h[n][d] = bf16(atom_emb0[x0][d] + atom_emb1[x1][d])
__global__ void atom_embed_kernel(const int* __restrict__ x,
                                  const float* __restrict__ emb0,
                                  const float* __restrict__ emb1,
                                  unsigned short* __restrict__ hbf, int n) {
    int idx = blockIdx.x * blockDim.x + threadIdx.x;
    if (idx >= n * 32) return;
    int node = idx >> 5;
    int d0 = (idx & 31) << 2;
    int i0 = x[node * 2 + 0];
    int i1 = x[node * 2 + 1];
    const float4 a = *reinterpret_cast<const float4*>(emb0 + (size_t)i0 * D + d0);
    const float4 b = *reinterpret_cast<const float4*>(emb1 + (size_t)i1 * D + d0);
    uint2 v;
    v.x = pack2(a.x + b.x, a.y + b.y);
    v.y = pack2(a.z + b.z, a.w + b.w);
    *reinterpret_cast<uint2*>(hbf + (size_t)node * D + d0) = v;
}

// ---- CSR build (once per launch) ----
__global__ void hist_kernel(const int* __restrict__ ei, int* __restrict__ counts, int e_cnt) {
    int e = blockIdx.x * blockDim.x + threadIdx.x;
    if (e >= e_cnt) return;
    atomicAdd(counts + ei[e_cnt + e], 1);
}

// stage 1: per-block (256 elems) sums
__global__ __launch_bounds__(256) void bsum_kernel(const int* __restrict__ counts,
                                                   int* __restrict__ bsum, int n) {
    __shared__ int s[256];
    int t = threadIdx.x;
    int idx = blockIdx.x * 256 + t;
    s[t] = (idx < n) ? counts[idx] : 0;
    __syncthreads();
    for (int off = 128; off > 0; off >>= 1) {
        if (t < off) s[t] += s[t + off];
        __syncthreads();
    }
    if (t == 0) bsum[blockIdx.x] = s[0];
}

// stage 2: single-block exclusive scan of <=256 block sums; also row_ptr[n]=total
__global__ __launch_bounds__(256) void bscan_kernel(const int* __restrict__ bsum,
                                                    int* __restrict__ bpre,
                                                    int* __restrict__ row_ptr, int nb, int n) {
    __shared__ int s[256];
    int t = threadIdx.x;
    s[t] = (t < nb) ? bsum[t] : 0;
    __syncthreads();
    for (int off = 1; off < 256; off <<= 1) {
        int v = (t >= off) ? s[t - off] : 0;
        __syncthreads();
        s[t] += v;
        __syncthreads();
    }
    bpre[t] = (t == 0) ? 0 : s[t - 1];
    if (t == 255) row_ptr[n] = s[255];
}

// stage 3: block-local exclusive scan + block prefix -> row_ptr, cursor
__global__ __launch_bounds__(256) void scan_apply_kernel(const int* __restrict__ counts,
                                                         const int* __restrict__ bpre,
                                                         int* __restrict__ row_ptr,
                                                         int* __restrict__ cursor, int n) {
    __shared__ int s[256];
    int t = threadIdx.x;
    int idx = blockIdx.x * 256 + t;
    int c = (idx < n) ? counts[idx] : 0;
    s[t] = c;
    __syncthreads();
    for (int off = 1; off < 256; off <<= 1) {
        int v = (t >= off) ? s[t - off] : 0;
        __syncthreads();
        s[t] += v;
        __syncthreads();
    }
    if (idx < n) {
        int excl = bpre[blockIdx.x] + s[t] - c;
        row_ptr[idx] = excl;
        cursor[idx] = excl;
    }
}

__global__ void fill_kernel(const int* __restrict__ ei, const int* __restrict__ ea,
                            int* __restrict__ cursor, int* __restrict__ epack, int e_cnt) {
    int e = blockIdx.x * blockDim.x + threadIdx.x;
    if (e >= e_cnt) return;
    int dst = ei[e_cnt + e];
    int src = ei[e];
    int aidx = ea[e * 2 + 0] * 3 + ea[e * 2 + 1];
    int pos = atomicAdd(cursor + dst, 1);
    epack[pos] = (src & 0x1FFFF) | (aidx << 17);
}

// ---- weight fragment pre-pack (bf16, per-lane MFMA B-operand layout) ----
__global__ void frag_prep_kernel(const float* __restrict__ W1,
                                 const float* __restrict__ W2,
                                 unsigned short* __restrict__ w1f,
                                 unsigned short* __restrict__ w2f, int Lnum) {
    int tid = blockIdx.x * blockDim.x + threadIdx.x;
    if (tid >= Lnum * 128 * 64) return;
    int l = tid / 8192;
    int rem = tid % 8192;
    int frag = rem / 64;
    int lane = rem % 64;
    int kg = lane >> 4, cl = lane & 15;
    if (frag < 64) {
        int kk = frag >> 4, tn = frag & 15;
        const float* src = W1 + (size_t)l * D * TWO_D;
        int k0 = kk * 32 + kg * 8, col = tn * 16 + cl;
        unsigned short* dst = w1f + (size_t)l * 32768 + ((size_t)frag * 64 + lane) * 8;
        #pragma unroll
        for (int j = 0; j < 8; ++j) dst[j] = f2bf(src[(size_t)(k0 + j) * TWO_D + col]);
    } else {
        int f2 = frag - 64;
        int kk = f2 >> 3, tn = f2 & 7;
        const float* src = W2 + (size_t)l * TWO_D * D;
        int k0 = kk * 32 + kg * 8, col = tn * 16 + cl;
        unsigned short* dst = w2f + (size_t)l * 32768 + ((size_t)f2 * 64 + lane) * 8;
        #pragma unroll
        for (int j = 0; j < 8; ++j) dst[j] = f2bf(src[(size_t)(k0 + j) * D + col]);
    }
}

// ---- gather over CSR with fused BN+ReLU of source values, 4-wide ILP ----
// aggr[v] = xform(h[v]) + cee[self] + sum_edges (xform(h[src]) + cee[aidx])
// xform(v) = do_bn ? relu(v*sc[d]+sh[d]) : v.
// Edge loop chunked by 4: 4 independent row loads in flight per half-wave.
__global__ __launch_bounds__(256) void gather_kernel(
    const unsigned short* __restrict__ hbf,
    const float* __restrict__ ee0_l, const float* __restrict__ ee1_l,
    const float* __restrict__ scsh,
    const int* __restrict__ row_ptr, const int* __restrict__ epack,
    unsigned short* __restrict__ aggrbf, float* __restrict__ stats,
    int n, int do_bn) {

    __shared__ float cee[16 * D];
    const int t = threadIdx.x;
    if (blockIdx.x == 0) stats[t] = 0.f;
    for (int i = t; i < 16 * D; i += 256) {
        int r = i >> 7, d = i & 127;
        cee[i] = (r < 15) ? ee0_l[(r / 3) * D + d] + ee1_l[(r % 3) * D + d]
                          : ee0_l[4 * D + d] + ee1_l[d];
    }
    __syncthreads();
    int node = blockIdx.x * 8 + (t >> 5);
    if (node >= n) return;
    int d0 = (t & 31) << 2;

    const int jb = row_ptr[node];
    const int je = row_ptr[node + 1];

    float4 sc, sh;
    if (do_bn) {
        sc = *reinterpret_cast<const float4*>(scsh + d0);
        sh = *reinterpret_cast<const float4*>(scsh + 128 + d0);
    } else {
        sc = make_float4(1.f, 1.f, 1.f, 1.f);
        sh = make_float4(0.f, 0.f, 0.f, 0.f);
    }

    float ax, ay, az, aw;
    {
        const float4 cs = *reinterpret_cast<const float4*>(cee + 15 * D + d0);
        uint2 hv = *reinterpret_cast<const uint2*>(hbf + (size_t)node * D + d0);
        if (do_bn) {
            ax = relu_f(bf2f(hv.x & 0xffffu) * sc.x + sh.x) + cs.x;
            ay = relu_f(bf2f(hv.x >> 16)     * sc.y + sh.y) + cs.y;
            az = relu_f(bf2f(hv.y & 0xffffu) * sc.z + sh.z) + cs.z;
            aw = relu_f(bf2f(hv.y >> 16)     * sc.w + sh.w) + cs.w;
        } else {
            ax = bf2f(hv.x & 0xffffu) + cs.x;
            ay = bf2f(hv.x >> 16)     + cs.y;
            az = bf2f(hv.y & 0xffffu) + cs.z;
            aw = bf2f(hv.y >> 16)     + cs.w;
        }
    }

    int j = jb;
    // main: 4 edges per iteration -> 4 row loads outstanding
    for (; j + 4 <= je; j += 4) {
        const int p0 = epack[j + 0];
        const int p1 = epack[j + 1];
        const int p2 = epack[j + 2];
        const int p3 = epack[j + 3];
        const uint2 s0 = *reinterpret_cast<const uint2*>(hbf + (size_t)(p0 & 0x1FFFF) * D + d0);
        const uint2 s1 = *reinterpret_cast<const uint2*>(hbf + (size_t)(p1 & 0x1FFFF) * D + d0);
        const uint2 s2 = *reinterpret_cast<const uint2*>(hbf + (size_t)(p2 & 0x1FFFF) * D + d0);
        const uint2 s3 = *reinterpret_cast<const uint2*>(hbf + (size_t)(p3 & 0x1FFFF) * D + d0);
        const float4 e0 = *reinterpret_cast<const float4*>(cee + (p0 >> 17) * D + d0);
        const float4 e1 = *reinterpret_cast<const float4*>(cee + (p1 >> 17) * D + d0);
        const float4 e2 = *reinterpret_cast<const float4*>(cee + (p2 >> 17) * D + d0);
        const float4 e3 = *reinterpret_cast<const float4*>(cee + (p3 >> 17) * D + d0);
        if (do_bn) {
            ax += relu_f(bf2f(s0.x & 0xffffu) * sc.x + sh.x) + e0.x;
            ay += relu_f(bf2f(s0.x >> 16)     * sc.y + sh.y) + e0.y;
            az += relu_f(bf2f(s0.y & 0xffffu) * sc.z + sh.z) + e0.z;
            aw += relu_f(bf2f(s0.y >> 16)     * sc.w + sh.w) + e0.w;
            ax += relu_f(bf2f(s1.x & 0xffffu) * sc.x + sh.x) + e1.x;
            ay += relu_f(bf2f(s1.x >> 16)     * sc.y + sh.y) + e1.y;
            az += relu_f(bf2f(s1.y & 0xffffu) * sc.z + sh.z) + e1.z;
            aw += relu_f(bf2f(s1.y >> 16)     * sc.w + sh.w) + e1.w;
            ax += relu_f(bf2f(s2.x & 0xffffu) * sc.x + sh.x) + e2.x;
            ay += relu_f(bf2f(s2.x >> 16)     * sc.y + sh.y) + e2.y;
            az += relu_f(bf2f(s2.y & 0xffffu) * sc.z + sh.z) + e2.z;
            aw += relu_f(bf2f(s2.y >> 16)     * sc.w + sh.w) + e2.w;
            ax += relu_f(bf2f(s3.x & 0xffffu) * sc.x + sh.x) + e3.x;
            ay += relu_f(bf2f(s3.x >> 16)     * sc.y + sh.y) + e3.y;
            az += relu_f(bf2f(s3.y & 0xffffu) * sc.z + sh.z) + e3.z;
            aw += relu_f(bf2f(s3.y >> 16)     * sc.w + sh.w) + e3.w;
        } else {
            ax += bf2f(s0.x & 0xffffu) + e0.x + bf2f(s1.x & 0xffffu) + e1.x
                + bf2f(s2.x & 0xffffu) + e2.x + bf2f(s3.x & 0xffffu) + e3.x;
            ay += bf2f(s0.x >> 16) + e0.y + bf2f(s1.x >> 16) + e1.y
                + bf2f(s2.x >> 16) + e2.y + bf2f(s3.x >> 16) + e3.y;
            az += bf2f(s0.y & 0xffffu) + e0.z + bf2f(s1.y & 0xffffu) + e1.z
                + bf2f(s2.y & 0xffffu) + e2.z + bf2f(s3.y & 0xffffu) + e3.z;
            aw += bf2f(s0.y >> 16) + e0.w + bf2f(s1.y >> 16) + e1.w
                + bf2f(s2.y >> 16) + e2.w + bf2f(s3.y >> 16) + e3.w;
        }
    }
    // tail: up to 3 edges
    for (; j < je; ++j) {
        const int p = epack[j];
        const uint2 sv = *reinterpret_cast<const uint2*>(hbf + (size_t)(p & 0x1FFFF) * D + d0);
        const float4 ev = *reinterpret_cast<const float4*>(cee + (p >> 17) * D + d0);
        if (do_bn) {
            ax += relu_f(bf2f(sv.x & 0xffffu) * sc.x + sh.x) + ev.x;
            ay += relu_f(bf2f(sv.x >> 16)     * sc.y + sh.y) + ev.y;
            az += relu_f(bf2f(sv.y & 0xffffu) * sc.z + sh.z) + ev.z;
            aw += relu_f(bf2f(sv.y >> 16)     * sc.w + sh.w) + ev.w;
        } else {
            ax += bf2f(sv.x & 0xffffu) + ev.x;
            ay += bf2f(sv.x >> 16)     + ev.y;
            az += bf2f(sv.y & 0xffffu) + ev.z;
            aw += bf2f(sv.y >> 16)     + ev.w;
        }
    }

    uint2 o;
    o.x = pack2(ax, ay);
    o.y = pack2(az, aw);
    *reinterpret_cast<uint2*>(aggrbf + (size_t)node * D + d0) = o;
}

// ---- MFMA fused MLP: out = relu(A@W1+b1)@W2 + b2, BN partial sums ----
__global__ __launch_bounds__(256) void mlp_mfma_kernel(
    unsigned short* __restrict__ aggrbf,
    const bf16x8* __restrict__ w1f, const bf16x8* __restrict__ w2f,
    const float* __restrict__ b1l, const float* __restrict__ b2l,
    float* __restrict__ outf, float* __restrict__ stats, int n, int final_f32) {

    __shared__ unsigned short hid[16 * TWO_D];   // 8 KB, XOR-swizzled
    __shared__ float sred[256];

    const int wave = threadIdx.x >> 6;
    const int lane = threadIdx.x & 63;
    const int arow = lane & 15;
    const int kgrp = lane >> 4;

    bf16x8 W1[4][4];
    #pragma unroll
    for (int kk = 0; kk < 4; ++kk)
        #pragma unroll
        for (int t = 0; t < 4; ++t)
            W1[kk][t] = w1f[(kk * 16 + wave * 4 + t) * 64 + lane];
    bf16x8 W2[8][2];
    #pragma unroll
    for (int kk = 0; kk < 8; ++kk)
        #pragma unroll
        for (int t = 0; t < 2; ++t)
            W2[kk][t] = w2f[(kk * 8 + wave * 2 + t) * 64 + lane];

    float b1v[4], b2v[2];
    #pragma unroll
    for (int t = 0; t < 4; ++t) b1v[t] = b1l[wave * 64 + t * 16 + arow];
    #pragma unroll
    for (int t = 0; t < 2; ++t) b2v[t] = b2l[wave * 32 + t * 16 + arow];

    float ps[2] = {0.f, 0.f}, pq[2] = {0.f, 0.f};

    const int tiles = n >> 4;       // n % 16 == 0
    for (int tile = blockIdx.x; tile < tiles; tile += gridDim.x) {
        const size_t row0 = (size_t)tile * 16;

        bf16x8 a[4];
        #pragma unroll
        for (int kk = 0; kk < 4; ++kk)
            a[kk] = *reinterpret_cast<const bf16x8*>(
                aggrbf + (row0 + arow) * D + kk * 32 + kgrp * 8);

        f32x4 acc1[4];
        #pragma unroll
        for (int t = 0; t < 4; ++t) acc1[t] = (f32x4){0.f, 0.f, 0.f, 0.f};
        #pragma unroll
        for (int kk = 0; kk < 4; ++kk)
            #pragma unroll
            for (int t = 0; t < 4; ++t)
                acc1[t] = __builtin_amdgcn_mfma_f32_16x16x32_bf16(a[kk], W1[kk][t], acc1[t], 0, 0, 0);

        __syncthreads();   // protect hid reads of previous iteration
        #pragma unroll
        for (int t = 0; t < 4; ++t) {
            const int cc = wave * 64 + t * 16 + arow;
            #pragma unroll
            for (int r = 0; r < 4; ++r) {
                const int rr = kgrp * 4 + r;
                float v = relu_f(acc1[t][r] + b1v[t]);
                hid[(rr * TWO_D + cc) ^ ((rr & 7) << 3)] = f2bf(v);
            }
        }
        __syncthreads();

        f32x4 acc2[2];
        #pragma unroll
        for (int t = 0; t < 2; ++t) acc2[t] = (f32x4){0.f, 0.f, 0.f, 0.f};
        #pragma unroll
        for (int kk = 0; kk < 8; ++kk) {
            bf16x8 a2 = *reinterpret_cast<const bf16x8*>(
                hid + ((arow * TWO_D + kk * 32 + kgrp * 8) ^ ((arow & 7) << 3)));
            #pragma unroll
            for (int t = 0; t < 2; ++t)
                acc2[t] = __builtin_amdgcn_mfma_f32_16x16x32_bf16(a2, W2[kk][t], acc2[t], 0, 0, 0);
        }

        if (final_f32) {
            #pragma unroll
            for (int t = 0; t < 2; ++t) {
                const int col = wave * 32 + t * 16 + arow;
                #pragma unroll
                for (int r = 0; r < 4; ++r) {
                    float v = acc2[t][r] + b2v[t];
                    outf[(row0 + kgrp * 4 + r) * D + col] = v;
                    ps[t] += v; pq[t] += v * v;
                }
            }
        } else {
            #pragma unroll
            for (int t = 0; t < 2; ++t) {
                const int col = wave * 32 + t * 16 + arow;
                #pragma unroll
                for (int r = 0; r < 4; ++r) {
                    float v = acc2[t][r] + b2v[t];
                    aggrbf[(row0 + kgrp * 4 + r) * D + col] = f2bf(v);
                    ps[t] += v; pq[t] += v * v;
                }
            }
        }
    }

    sred[threadIdx.x] = 0.f;
    __syncthreads();
    #pragma unroll
    for (int t = 0; t < 2; ++t) {
        const int col = wave * 32 + t * 16 + arow;
        atomicAdd(sred + col, ps[t]);
        atomicAdd(sred + 128 + col, pq[t]);
    }
    __syncthreads();
    unsafeAtomicAdd(stats + threadIdx.x, sred[threadIdx.x]);
}

__global__ void bn_scale_kernel(const float* __restrict__ stats,
                                const float* __restrict__ gamma_l,
                                const float* __restrict__ beta_l,
                                float* __restrict__ scsh, float inv_n) {
    int c = threadIdx.x;   // 128
    float mean = stats[c] * inv_n;
    float var  = stats[128 + c] * inv_n - mean * mean;
    float sc = gamma_l[c] * rsqrtf(var + BN_EPS);
    scsh[c]       = sc;
    scsh[128 + c] = beta_l[c] - mean * sc;
}

// final layer: d_out = out*sc+sh (f32, no relu)
__global__ void bn_apply_final_kernel(const float* __restrict__ out,
                                      const float* __restrict__ scsh,
                                      float* __restrict__ dst, int n) {
    int idx = blockIdx.x * blockDim.x + threadIdx.x;
    if (idx >= n * 32) return;
    int d0 = (idx & 31) << 2;
    float4 v  = *reinterpret_cast<const float4*>(out + (size_t)idx * 4);
    float4 sc = *reinterpret_cast<const float4*>(scsh + d0);
    float4 sh = *reinterpret_cast<const float4*>(scsh + 128 + d0);
    *reinterpret_cast<float4*>(dst + (size_t)idx * 4) =
        make_float4(v.x * sc.x + sh.x, v.y * sc.y + sh.y,
                    v.z * sc.z + sh.z, v.w * sc.w + sh.w);
}

extern "C" void kernel_launch(void* const* d_in, const int* in_sizes, int n_in,
                              void* d_out, int out_size, void* d_ws, size_t ws_size,
                              hipStream_t stream) {
    const int*   x     = (const int*)d_in[0];
    const int*   ei    = (const int*)d_in[1];
    const int*   ea    = (const int*)d_in[2];
    const float* aemb0 = (const float*)d_in[3];
    const float* aemb1 = (const float*)d_in[4];
    const float* eemb0 = (const float*)d_in[5];
    const float* eemb1 = (const float*)d_in[6];
    const float* W1    = (const float*)d_in[7];
    const float* b1    = (const float*)d_in[8];
    const float* W2    = (const float*)d_in[9];
    const float* b2    = (const float*)d_in[10];
    const float* gamma = (const float*)d_in[11];
    const float* beta  = (const float*)d_in[12];

    const int n = in_sizes[0] / 2;          // 50000
    const int e = in_sizes[1] / 2;          // 500000
    const int L = in_sizes[8] / TWO_D;      // 3

    char* ws = (char*)d_ws;
    float* outb = (float*)ws;                      ws += (size_t)n * D * 4;
    unsigned short* bufA = (unsigned short*)ws;    ws += (size_t)n * D * 2;
    unsigned short* bufB = (unsigned short*)ws;    ws += (size_t)n * D * 2;
    unsigned short* w1f = (unsigned short*)ws;     ws += (size_t)L * 32768 * 2;
    unsigned short* w2f = (unsigned short*)ws;     ws += (size_t)L * 32768 * 2;
    float* stats = (float*)ws;                     ws += 256 * 4;
    float* scsh  = (float*)ws;                     ws += 256 * 4;
    int* counts  = (int*)ws;                       ws += (size_t)n * 4;
    int* row_ptr = (int*)ws;                       ws += (size_t)(n + 1) * 4;
    int* cursor  = (int*)ws;                       ws += (size_t)n * 4;
    int* bsum    = (int*)ws;                       ws += 256 * 4;
    int* bpre    = (int*)ws;                       ws += 256 * 4;
    int* epack   = (int*)ws;

    const int edge_blocks = (e + 255) / 256;
    const int vec_blocks  = (n * 32 + 255) / 256;
    const int node_blocks = (n + 7) / 8;
    const int nb = (n + 255) / 256;          // 196 <= 256

    hipMemsetAsync(counts, 0, (size_t)n * sizeof(int), stream);
    hist_kernel<<<edge_blocks, 256, 0, stream>>>(ei, counts, e);
    bsum_kernel<<<nb, 256, 0, stream>>>(counts, bsum, n);
    bscan_kernel<<<1, 256, 0, stream>>>(bsum, bpre, row_ptr, nb, n);
    scan_apply_kernel<<<nb, 256, 0, stream>>>(counts, bpre, row_ptr, cursor, n);
    fill_kernel<<<edge_blocks, 256, 0, stream>>>(ei, ea, cursor, epack, e);
    frag_prep_kernel<<<(L * 128 * 64 + 255) / 256, 256, 0, stream>>>(W1, W2, w1f, w2f, L);
    atom_embed_kernel<<<vec_blocks, 256, 0, stream>>>(x, aemb0, aemb1, bufA, n);

    for (int l = 0; l < L; ++l) {
        const float* ee0_l = eemb0 + (size_t)l * 5 * D;
        const float* ee1_l = eemb1 + (size_t)l * 3 * D;
        const float* b1l   = b1 + (size_t)l * TWO_D;
        const float* b2l   = b2 + (size_t)l * D;

        unsigned short* src = (l & 1) ? bufB : bufA;   // previous layer's values
        unsigned short* dst = (l & 1) ? bufA : bufB;   // gather out + mlp in/out

        gather_kernel<<<node_blocks, 256, 0, stream>>>(src, ee0_l, ee1_l, scsh,
                                                       row_ptr, epack, dst, stats,
                                                       n, (l > 0) ? 1 : 0);
        mlp_mfma_kernel<<<512, 256, 0, stream>>>(
            dst,
            (const bf16x8*)(w1f + (size_t)l * 32768),
            (const bf16x8*)(w2f + (size_t)l * 32768),
            b1l, b2l, outb, stats, n, (l == L - 1) ? 1 : 0);
        bn_scale_kernel<<<1, D, 0, stream>>>(stats, gamma + (size_t)l * D, beta + (size_t)l * D,
                                             scsh, 1.0f / (float)n);
    }
    bn_apply_final_kernel<<<vec_blocks, 256, 0, stream>>>(outb, scsh, (float*)d_out, n);
}

// Round 6
// 278.767 us; speedup vs baseline: 10.8312x; 1.0652x over previous
//
#include <hip/hip_runtime.h>

#define D 128
#define TWO_D 256
#define BN_EPS 1e-5f

typedef __attribute__((ext_vector_type(8))) short bf16x8;   // 8 bf16 = 4 VGPR
typedef __attribute__((ext_vector_type(4))) float f32x4;

__device__ __forceinline__ float relu_f(float x) { return x > 0.f ? x : 0.f; }

__device__ __forceinline__ unsigned short f2bf(float f) {   // RTN-even
    unsigned u = __builtin_bit_cast(unsigned, f);
    return (unsigned short)((u + 0x7FFFu + ((u >> 16) & 1u)) >> 16);
}
__device__ __forceinline__ float bf2f(unsigned s) {
    unsigned u = s << 16;
    return __builtin_bit_cast(float, u);
}
__device__ __forceinline__ unsigned pack2(float a, float b) {
    return (unsigned)f2bf(a) | ((unsigned)f2bf(b) << 16);
}

// h[n][d] = bf16(atom_emb0[x0][d] + atom_emb1[x1][d])
__global__ void atom_embed_kernel(const int* __restrict__ x,
                                  const float* __restrict__ emb0,
                                  const float* __restrict__ emb1,
                                  unsigned short* __restrict__ hbf, int n) {
    int idx = blockIdx.x * blockDim.x + threadIdx.x;
    if (idx >= n * 32) return;
    int node = idx >> 5;
    int d0 = (idx & 31) << 2;
    int i0 = x[node * 2 + 0];
    int i1 = x[node * 2 + 1];
    const float4 a = *reinterpret_cast<const float4*>(emb0 + (size_t)i0 * D + d0);
    const float4 b = *reinterpret_cast<const float4*>(emb1 + (size_t)i1 * D + d0);
    uint2 v;
    v.x = pack2(a.x + b.x, a.y + b.y);
    v.y = pack2(a.z + b.z, a.w + b.w);
    *reinterpret_cast<uint2*>(hbf + (size_t)node * D + d0) = v;
}

// ---- CSR build (once per launch) ----
__global__ void hist_kernel(const int* __restrict__ ei, int* __restrict__ counts, int e_cnt) {
    int e = blockIdx.x * blockDim.x + threadIdx.x;
    if (e >= e_cnt) return;
    atomicAdd(counts + ei[e_cnt + e], 1);
}

__global__ __launch_bounds__(256) void bsum_kernel(const int* __restrict__ counts,
                                                   int* __restrict__ bsum, int n) {
    __shared__ int s[256];
    int t = threadIdx.x;
    int idx = blockIdx.x * 256 + t;
    s[t] = (idx < n) ? counts[idx] : 0;
    __syncthreads();
    for (int off = 128; off > 0; off >>= 1) {
        if (t < off) s[t] += s[t + off];
        __syncthreads();
    }
    if (t == 0) bsum[blockIdx.x] = s[0];
}

__global__ __launch_bounds__(256) void bscan_kernel(const int* __restrict__ bsum,
                                                    int* __restrict__ bpre,
                                                    int* __restrict__ row_ptr, int nb, int n) {
    __shared__ int s[256];
    int t = threadIdx.x;
    s[t] = (t < nb) ? bsum[t] : 0;
    __syncthreads();
    for (int off = 1; off < 256; off <<= 1) {
        int v = (t >= off) ? s[t - off] : 0;
        __syncthreads();
        s[t] += v;
        __syncthreads();
    }
    bpre[t] = (t == 0) ? 0 : s[t - 1];
    if (t == 255) row_ptr[n] = s[255];
}

__global__ __launch_bounds__(256) void scan_apply_kernel(const int* __restrict__ counts,
                                                         const int* __restrict__ bpre,
                                                         int* __restrict__ row_ptr,
                                                         int* __restrict__ cursor, int n) {
    __shared__ int s[256];
    int t = threadIdx.x;
    int idx = blockIdx.x * 256 + t;
    int c = (idx < n) ? counts[idx] : 0;
    s[t] = c;
    __syncthreads();
    for (int off = 1; off < 256; off <<= 1) {
        int v = (t >= off) ? s[t - off] : 0;
        __syncthreads();
        s[t] += v;
        __syncthreads();
    }
    if (idx < n) {
        int excl = bpre[blockIdx.x] + s[t] - c;
        row_ptr[idx] = excl;
        cursor[idx] = excl;
    }
}

__global__ void fill_kernel(const int* __restrict__ ei, const int* __restrict__ ea,
                            int* __restrict__ cursor, int* __restrict__ epack, int e_cnt) {
    int e = blockIdx.x * blockDim.x + threadIdx.x;
    if (e >= e_cnt) return;
    int dst = ei[e_cnt + e];
    int src = ei[e];
    int aidx = ea[e * 2 + 0] * 3 + ea[e * 2 + 1];   // in [0,9)
    int pos = atomicAdd(cursor + dst, 1);
    epack[pos] = (src & 0x1FFFF) | (aidx << 17);
}

// ---- weight fragment pre-pack (bf16, per-lane MFMA B-operand layout) ----
__global__ void frag_prep_kernel(const float* __restrict__ W1,
                                 const float* __restrict__ W2,
                                 unsigned short* __restrict__ w1f,
                                 unsigned short* __restrict__ w2f, int Lnum) {
    int tid = blockIdx.x * blockDim.x + threadIdx.x;
    if (tid >= Lnum * 128 * 64) return;
    int l = tid / 8192;
    int rem = tid % 8192;
    int frag = rem / 64;
    int lane = rem % 64;
    int kg = lane >> 4, cl = lane & 15;
    if (frag < 64) {
        int kk = frag >> 4, tn = frag & 15;
        const float* src = W1 + (size_t)l * D * TWO_D;
        int k0 = kk * 32 + kg * 8, col = tn * 16 + cl;
        unsigned short* dst = w1f + (size_t)l * 32768 + ((size_t)frag * 64 + lane) * 8;
        #pragma unroll
        for (int j = 0; j < 8; ++j) dst[j] = f2bf(src[(size_t)(k0 + j) * TWO_D + col]);
    } else {
        int f2 = frag - 64;
        int kk = f2 >> 3, tn = f2 & 7;
        const float* src = W2 + (size_t)l * TWO_D * D;
        int k0 = kk * 32 + kg * 8, col = tn * 16 + cl;
        unsigned short* dst = w2f + (size_t)l * 32768 + ((size_t)f2 * 64 + lane) * 8;
        #pragma unroll
        for (int j = 0; j < 8; ++j) dst[j] = f2bf(src[(size_t)(k0 + j) * D + col]);
    }
}

// ---- gather over CSR, 8-deep ILP, LDS-free hot loop ----
// aggr[v] = xf(h[v]) + cee[15] + sum_edges xf(h[src]) + sum_a cnt[a]*cee[a]
// xf(v) = DO_BN ? relu(v*sc[d]+sh[d]) : v ; sc/sh computed per-block from
// stats_prev (fused bn_scale). Block 0 zeroes stats_cur for this layer's MLP.
template<int DO_BN>
__global__ __launch_bounds__(256) void gather_kernel(
    const unsigned short* __restrict__ hbf,
    const float* __restrict__ ee0_l, const float* __restrict__ ee1_l,
    const float* __restrict__ stats_prev,
    const float* __restrict__ gamma_p, const float* __restrict__ beta_p,
    float inv_n,
    const int* __restrict__ row_ptr, const int* __restrict__ epack,
    unsigned short* __restrict__ aggrbf, float* __restrict__ stats_cur, int n) {

    __shared__ float cee[16 * D];
    __shared__ float sbn[2 * D];
    const int t = threadIdx.x;
    if (blockIdx.x == 0) stats_cur[t] = 0.f;
    for (int i = t; i < 16 * D; i += 256) {
        int r = i >> 7, d = i & 127;
        cee[i] = (r < 15) ? ee0_l[(r / 3) * D + d] + ee1_l[(r % 3) * D + d]
                          : ee0_l[4 * D + d] + ee1_l[d];
    }
    if (DO_BN && t < 128) {
        float mean = stats_prev[t] * inv_n;
        float var  = stats_prev[128 + t] * inv_n - mean * mean;
        float sc = gamma_p[t] * rsqrtf(var + BN_EPS);
        sbn[t] = sc;
        sbn[128 + t] = beta_p[t] - mean * sc;
    }
    __syncthreads();

    int node = blockIdx.x * 8 + (t >> 5);
    if (node >= n) return;
    int d0 = (t & 31) << 2;

    float4 sc = make_float4(1.f, 1.f, 1.f, 1.f);
    float4 sh = make_float4(0.f, 0.f, 0.f, 0.f);
    if (DO_BN) {
        sc = *reinterpret_cast<const float4*>(sbn + d0);
        sh = *reinterpret_cast<const float4*>(sbn + 128 + d0);
    }

    const int jb = row_ptr[node];
    const int je = row_ptr[node + 1];

    float ax, ay, az, aw;
    {
        const float4 cs = *reinterpret_cast<const float4*>(cee + 15 * D + d0);
        uint2 hv = *reinterpret_cast<const uint2*>(hbf + (size_t)node * D + d0);
        if (DO_BN) {
            ax = relu_f(bf2f(hv.x & 0xffffu) * sc.x + sh.x) + cs.x;
            ay = relu_f(bf2f(hv.x >> 16)     * sc.y + sh.y) + cs.y;
            az = relu_f(bf2f(hv.y & 0xffffu) * sc.z + sh.z) + cs.z;
            aw = relu_f(bf2f(hv.y >> 16)     * sc.w + sh.w) + cs.w;
        } else {
            ax = bf2f(hv.x & 0xffffu) + cs.x;
            ay = bf2f(hv.x >> 16)     + cs.y;
            az = bf2f(hv.y & 0xffffu) + cs.z;
            aw = bf2f(hv.y >> 16)     + cs.w;
        }
    }

    unsigned long long c0 = 0ull;   // 8x 8-bit counts for aidx 0..7
    int cnt8 = 0;                   // count for aidx == 8

#define ROWLD(p) (*reinterpret_cast<const uint2*>(hbf + (size_t)((p) & 0x1FFFF) * D + d0))
#define CNTUPD(p) do { int a_ = (p) >> 17; \
        unsigned long long bit_ = 1ull << ((a_ & 7) << 3); \
        c0 += (a_ < 8) ? bit_ : 0ull; cnt8 += (a_ >> 3); } while (0)
#define EACC(sv) do { \
        if (DO_BN) { \
            ax += relu_f(bf2f((sv).x & 0xffffu) * sc.x + sh.x); \
            ay += relu_f(bf2f((sv).x >> 16)     * sc.y + sh.y); \
            az += relu_f(bf2f((sv).y & 0xffffu) * sc.z + sh.z); \
            aw += relu_f(bf2f((sv).y >> 16)     * sc.w + sh.w); \
        } else { \
            ax += bf2f((sv).x & 0xffffu); ay += bf2f((sv).x >> 16); \
            az += bf2f((sv).y & 0xffffu); aw += bf2f((sv).y >> 16); \
        } } while (0)

    int j = jb;
    for (; j + 8 <= je; j += 8) {
        const int p0 = epack[j + 0], p1 = epack[j + 1], p2 = epack[j + 2], p3 = epack[j + 3];
        const int p4 = epack[j + 4], p5 = epack[j + 5], p6 = epack[j + 6], p7 = epack[j + 7];
        const uint2 s0 = ROWLD(p0), s1 = ROWLD(p1), s2 = ROWLD(p2), s3 = ROWLD(p3);
        const uint2 s4 = ROWLD(p4), s5 = ROWLD(p5), s6 = ROWLD(p6), s7 = ROWLD(p7);
        CNTUPD(p0); CNTUPD(p1); CNTUPD(p2); CNTUPD(p3);
        CNTUPD(p4); CNTUPD(p5); CNTUPD(p6); CNTUPD(p7);
        EACC(s0); EACC(s1); EACC(s2); EACC(s3);
        EACC(s4); EACC(s5); EACC(s6); EACC(s7);
    }
    for (; j < je; ++j) {
        const int p = epack[j];
        const uint2 sv = ROWLD(p);
        CNTUPD(p);
        EACC(sv);
    }

    // expand aidx-count contributions once per node
    #pragma unroll
    for (int a = 0; a < 8; ++a) {
        float fc = (float)((unsigned)(c0 >> (a * 8)) & 0xFFu);
        const float4 ev = *reinterpret_cast<const float4*>(cee + a * D + d0);
        ax += fc * ev.x; ay += fc * ev.y; az += fc * ev.z; aw += fc * ev.w;
    }
    {
        float fc = (float)cnt8;
        const float4 ev = *reinterpret_cast<const float4*>(cee + 8 * D + d0);
        ax += fc * ev.x; ay += fc * ev.y; az += fc * ev.z; aw += fc * ev.w;
    }

    uint2 o;
    o.x = pack2(ax, ay);
    o.y = pack2(az, aw);
    *reinterpret_cast<uint2*>(aggrbf + (size_t)node * D + d0) = o;
#undef ROWLD
#undef CNTUPD
#undef EACC
}

// ---- MFMA fused MLP, paired 32-row tiles: 2 barriers per 2 tiles ----
__global__ __launch_bounds__(256) void mlp_mfma_kernel(
    unsigned short* __restrict__ aggrbf,
    const bf16x8* __restrict__ w1f, const bf16x8* __restrict__ w2f,
    const float* __restrict__ b1l, const float* __restrict__ b2l,
    float* __restrict__ outf, float* __restrict__ stats, int n, int final_f32) {

    __shared__ unsigned short hid[32 * TWO_D];   // 16 KB, XOR-swizzled
    __shared__ float sred[256];

    const int wave = threadIdx.x >> 6;
    const int lane = threadIdx.x & 63;
    const int arow = lane & 15;
    const int kgrp = lane >> 4;

    bf16x8 W1[4][4];
    #pragma unroll
    for (int kk = 0; kk < 4; ++kk)
        #pragma unroll
        for (int t = 0; t < 4; ++t)
            W1[kk][t] = w1f[(kk * 16 + wave * 4 + t) * 64 + lane];
    bf16x8 W2[8][2];
    #pragma unroll
    for (int kk = 0; kk < 8; ++kk)
        #pragma unroll
        for (int t = 0; t < 2; ++t)
            W2[kk][t] = w2f[(kk * 8 + wave * 2 + t) * 64 + lane];

    float b1v[4], b2v[2];
    #pragma unroll
    for (int t = 0; t < 4; ++t) b1v[t] = b1l[wave * 64 + t * 16 + arow];
    #pragma unroll
    for (int t = 0; t < 2; ++t) b2v[t] = b2l[wave * 32 + t * 16 + arow];

    float ps[2] = {0.f, 0.f}, pq[2] = {0.f, 0.f};

    const int tiles = n >> 4;            // n % 16 == 0
    const int npair = (tiles + 1) >> 1;
    for (int p = blockIdx.x; p < npair; p += gridDim.x) {
        const int t0i = 2 * p, t1i = 2 * p + 1;
        const bool has1 = (t1i < tiles);
        const size_t r0 = (size_t)t0i * 16, r1 = (size_t)t1i * 16;

        bf16x8 a0[4], a1[4];
        #pragma unroll
        for (int kk = 0; kk < 4; ++kk)
            a0[kk] = *reinterpret_cast<const bf16x8*>(
                aggrbf + (r0 + arow) * D + kk * 32 + kgrp * 8);
        if (has1) {
            #pragma unroll
            for (int kk = 0; kk < 4; ++kk)
                a1[kk] = *reinterpret_cast<const bf16x8*>(
                    aggrbf + (r1 + arow) * D + kk * 32 + kgrp * 8);
        }

        // GEMM1 tile0
        f32x4 acc1[4];
        #pragma unroll
        for (int t = 0; t < 4; ++t) acc1[t] = (f32x4){0.f, 0.f, 0.f, 0.f};
        #pragma unroll
        for (int kk = 0; kk < 4; ++kk)
            #pragma unroll
            for (int t = 0; t < 4; ++t)
                acc1[t] = __builtin_amdgcn_mfma_f32_16x16x32_bf16(a0[kk], W1[kk][t], acc1[t], 0, 0, 0);

        __syncthreads();   // prev iteration's hid reads complete
        #pragma unroll
        for (int t = 0; t < 4; ++t) {
            const int cc = wave * 64 + t * 16 + arow;
            #pragma unroll
            for (int r = 0; r < 4; ++r) {
                const int rr = kgrp * 4 + r;
                hid[(rr * TWO_D + cc) ^ ((rr & 7) << 3)] = f2bf(relu_f(acc1[t][r] + b1v[t]));
            }
        }

        // GEMM1 tile1
        if (has1) {
            #pragma unroll
            for (int t = 0; t < 4; ++t) acc1[t] = (f32x4){0.f, 0.f, 0.f, 0.f};
            #pragma unroll
            for (int kk = 0; kk < 4; ++kk)
                #pragma unroll
                for (int t = 0; t < 4; ++t)
                    acc1[t] = __builtin_amdgcn_mfma_f32_16x16x32_bf16(a1[kk], W1[kk][t], acc1[t], 0, 0, 0);
            #pragma unroll
            for (int t = 0; t < 4; ++t) {
                const int cc = wave * 64 + t * 16 + arow;
                #pragma unroll
                for (int r = 0; r < 4; ++r) {
                    const int rr = 16 + kgrp * 4 + r;
                    hid[(rr * TWO_D + cc) ^ ((rr & 7) << 3)] = f2bf(relu_f(acc1[t][r] + b1v[t]));
                }
            }
        }
        __syncthreads();

        // GEMM2 tile0
        {
            f32x4 acc2[2];
            #pragma unroll
            for (int t = 0; t < 2; ++t) acc2[t] = (f32x4){0.f, 0.f, 0.f, 0.f};
            #pragma unroll
            for (int kk = 0; kk < 8; ++kk) {
                bf16x8 a2 = *reinterpret_cast<const bf16x8*>(
                    hid + ((arow * TWO_D + kk * 32 + kgrp * 8) ^ ((arow & 7) << 3)));
                #pragma unroll
                for (int t = 0; t < 2; ++t)
                    acc2[t] = __builtin_amdgcn_mfma_f32_16x16x32_bf16(a2, W2[kk][t], acc2[t], 0, 0, 0);
            }
            #pragma unroll
            for (int t = 0; t < 2; ++t) {
                const int col = wave * 32 + t * 16 + arow;
                #pragma unroll
                for (int r = 0; r < 4; ++r) {
                    float v = acc2[t][r] + b2v[t];
                    if (final_f32) outf[(r0 + kgrp * 4 + r) * D + col] = v;
                    else           aggrbf[(r0 + kgrp * 4 + r) * D + col] = f2bf(v);
                    ps[t] += v; pq[t] += v * v;
                }
            }
        }
        // GEMM2 tile1
        if (has1) {
            f32x4 acc2[2];
            #pragma unroll
            for (int t = 0; t < 2; ++t) acc2[t] = (f32x4){0.f, 0.f, 0.f, 0.f};
            #pragma unroll
            for (int kk = 0; kk < 8; ++kk) {
                bf16x8 a2 = *reinterpret_cast<const bf16x8*>(
                    hid + (((16 + arow) * TWO_D + kk * 32 + kgrp * 8) ^ ((arow & 7) << 3)));
                #pragma unroll
                for (int t = 0; t < 2; ++t)
                    acc2[t] = __builtin_amdgcn_mfma_f32_16x16x32_bf16(a2, W2[kk][t], acc2[t], 0, 0, 0);
            }
            #pragma unroll
            for (int t = 0; t < 2; ++t) {
                const int col = wave * 32 + t * 16 + arow;
                #pragma unroll
                for (int r = 0; r < 4; ++r) {
                    float v = acc2[t][r] + b2v[t];
                    if (final_f32) outf[(r1 + kgrp * 4 + r) * D + col] = v;
                    else           aggrbf[(r1 + kgrp * 4 + r) * D + col] = f2bf(v);
                    ps[t] += v; pq[t] += v * v;
                }
            }
        }
    }

    sred[threadIdx.x] = 0.f;
    __syncthreads();
    #pragma unroll
    for (int t = 0; t < 2; ++t) {
        const int col = wave * 32 + t * 16 + arow;
        atomicAdd(sred + col, ps[t]);
        atomicAdd(sred + 128 + col, pq[t]);
    }
    __syncthreads();
    unsafeAtomicAdd(stats + threadIdx.x, sred[threadIdx.x]);
}

// final layer: d_out = out*sc+sh (f32, no relu); sc/sh computed per block
__global__ void bn_apply_final_kernel(const float* __restrict__ out,
                                      const float* __restrict__ stats,
                                      const float* __restrict__ gamma_l,
                                      const float* __restrict__ beta_l,
                                      float inv_n,
                                      float* __restrict__ dst, int n) {
    __shared__ float sbn[2 * D];
    int t = threadIdx.x;
    if (t < 128) {
        float mean = stats[t] * inv_n;
        float var  = stats[128 + t] * inv_n - mean * mean;
        float sc = gamma_l[t] * rsqrtf(var + BN_EPS);
        sbn[t] = sc;
        sbn[128 + t] = beta_l[t] - mean * sc;
    }
    __syncthreads();
    int idx = blockIdx.x * blockDim.x + t;
    if (idx >= n * 32) return;
    int d0 = (idx & 31) << 2;
    float4 v  = *reinterpret_cast<const float4*>(out + (size_t)idx * 4);
    float4 sc = *reinterpret_cast<const float4*>(sbn + d0);
    float4 sh = *reinterpret_cast<const float4*>(sbn + 128 + d0);
    *reinterpret_cast<float4*>(dst + (size_t)idx * 4) =
        make_float4(v.x * sc.x + sh.x, v.y * sc.y + sh.y,
                    v.z * sc.z + sh.z, v.w * sc.w + sh.w);
}

extern "C" void kernel_launch(void* const* d_in, const int* in_sizes, int n_in,
                              void* d_out, int out_size, void* d_ws, size_t ws_size,
                              hipStream_t stream) {
    const int*   x     = (const int*)d_in[0];
    const int*   ei    = (const int*)d_in[1];
    const int*   ea    = (const int*)d_in[2];
    const float* aemb0 = (const float*)d_in[3];
    const float* aemb1 = (const float*)d_in[4];
    const float* eemb0 = (const float*)d_in[5];
    const float* eemb1 = (const float*)d_in[6];
    const float* W1    = (const float*)d_in[7];
    const float* b1    = (const float*)d_in[8];
    const float* W2    = (const float*)d_in[9];
    const float* b2    = (const float*)d_in[10];
    const float* gamma = (const float*)d_in[11];
    const float* beta  = (const float*)d_in[12];

    const int n = in_sizes[0] / 2;          // 50000
    const int e = in_sizes[1] / 2;          // 500000
    const int L = in_sizes[8] / TWO_D;      // 3
    const float inv_n = 1.0f / (float)n;

    char* ws = (char*)d_ws;
    float* outb = (float*)ws;                      ws += (size_t)n * D * 4;
    unsigned short* bufA = (unsigned short*)ws;    ws += (size_t)n * D * 2;
    unsigned short* bufB = (unsigned short*)ws;    ws += (size_t)n * D * 2;
    unsigned short* w1f = (unsigned short*)ws;     ws += (size_t)L * 32768 * 2;
    unsigned short* w2f = (unsigned short*)ws;     ws += (size_t)L * 32768 * 2;
    float* statsA = (float*)ws;                    ws += 256 * 4;
    float* statsB = (float*)ws;                    ws += 256 * 4;
    int* counts  = (int*)ws;                       ws += (size_t)n * 4;
    int* row_ptr = (int*)ws;                       ws += (size_t)(n + 1) * 4;
    int* cursor  = (int*)ws;                       ws += (size_t)n * 4;
    int* bsum    = (int*)ws;                       ws += 256 * 4;
    int* bpre    = (int*)ws;                       ws += 256 * 4;
    int* epack   = (int*)ws;

    const int edge_blocks = (e + 255) / 256;
    const int vec_blocks  = (n * 32 + 255) / 256;
    const int node_blocks = (n + 7) / 8;
    const int nb = (n + 255) / 256;          // 196 <= 256

    hipMemsetAsync(counts, 0, (size_t)n * sizeof(int), stream);
    hist_kernel<<<edge_blocks, 256, 0, stream>>>(ei, counts, e);
    bsum_kernel<<<nb, 256, 0, stream>>>(counts, bsum, n);
    bscan_kernel<<<1, 256, 0, stream>>>(bsum, bpre, row_ptr, nb, n);
    scan_apply_kernel<<<nb, 256, 0, stream>>>(counts, bpre, row_ptr, cursor, n);
    fill_kernel<<<edge_blocks, 256, 0, stream>>>(ei, ea, cursor, epack, e);
    frag_prep_kernel<<<(L * 128 * 64 + 255) / 256, 256, 0, stream>>>(W1, W2, w1f, w2f, L);
    atom_embed_kernel<<<vec_blocks, 256, 0, stream>>>(x, aemb0, aemb1, bufA, n);

    for (int l = 0; l < L; ++l) {
        const float* ee0_l = eemb0 + (size_t)l * 5 * D;
        const float* ee1_l = eemb1 + (size_t)l * 3 * D;
        const float* b1l   = b1 + (size_t)l * TWO_D;
        const float* b2l   = b2 + (size_t)l * D;

        unsigned short* src = (l & 1) ? bufB : bufA;
        unsigned short* dst = (l & 1) ? bufA : bufB;
        float* stats_cur  = (l & 1) ? statsB : statsA;
        float* stats_prev = (l & 1) ? statsA : statsB;

        if (l == 0)
            gather_kernel<0><<<node_blocks, 256, 0, stream>>>(
                src, ee0_l, ee1_l, nullptr, nullptr, nullptr, inv_n,
                row_ptr, epack, dst, stats_cur, n);
        else
            gather_kernel<1><<<node_blocks, 256, 0, stream>>>(
                src, ee0_l, ee1_l, stats_prev,
                gamma + (size_t)(l - 1) * D, beta + (size_t)(l - 1) * D, inv_n,
                row_ptr, epack, dst, stats_cur, n);

        mlp_mfma_kernel<<<512, 256, 0, stream>>>(
            dst,
            (const bf16x8*)(w1f + (size_t)l * 32768),
            (const bf16x8*)(w2f + (size_t)l * 32768),
            b1l, b2l, outb, stats_cur, n, (l == L - 1) ? 1 : 0);
    }

    float* stats_last = ((L - 1) & 1) ? statsB : statsA;
    bn_apply_final_kernel<<<vec_blocks, 256, 0, stream>>>(
        outb, stats_last, gamma + (size_t)(L - 1) * D, beta + (size_t)(L - 1) * D,
        inv_n, (float*)d_out, n);
}